// Round 11
// baseline (756.954 us; speedup 1.0000x reference)
//
#include <hip/hip_runtime.h>

typedef __attribute__((ext_vector_type(8))) short short8;
typedef __attribute__((ext_vector_type(4))) float floatx4;
typedef unsigned int u32;

#define DIM 384
#define NHEAD 12
#define HDIM 32

__device__ __forceinline__ float bf2f(unsigned int u) {
    union { unsigned int i; float f; } x; x.i = (u & 0xffffu) << 16; return x.f;
}
__device__ __forceinline__ unsigned short f2bf(float f) {
    union { float f; unsigned int i; } x; x.f = f;
    return (unsigned short)((x.i + 0x7fffu + ((x.i >> 16) & 1u)) >> 16);
}

__device__ __forceinline__ int nat2win(int r) {
    int b = r / 3136; int l = r - b * 3136;
    int hh = l / 56, wc = l - hh * 56;
    int wh = hh / 7, nr = hh - wh * 7;
    int ww = wc / 7, nc = wc - ww * 7;
    return ((b << 6) + wh * 8 + ww) * 49 + nr * 7 + nc;
}
__device__ __forceinline__ int win2nat(int r) {
    int w = r / 49; int n = r - w * 49;
    int b = w >> 6; int wi = w & 63;
    int wh = wi >> 3, ww = wi & 7;
    int hh = wh * 7 + n / 7, wc = ww * 7 + n % 7;
    return b * 3136 + hh * 56 + wc;
}

#define GLOAD_LDS16(g, l) \
    __builtin_amdgcn_global_load_lds((const __attribute__((address_space(1))) u32*)(g), \
                                     (__attribute__((address_space(3))) u32*)(l), 16, 0, 0)

#define LDS_U32(p) ((u32)(uintptr_t)(__attribute__((address_space(3))) unsigned short*)(p))

// Opaque LDS read (compiler cannot tie it to gload_lds writes -> no auto-drain).
template <int OFF>
__device__ __forceinline__ short8 ds_read128(u32 addr) {
    short8 r;
    asm volatile("ds_read_b128 %0, %1 offset:%2" : "=v"(r) : "v"(addr), "i"(OFF));
    return r;
}
// Opaque global load (pins FIFO order for hand-counted vmcnt; result is valid
// only after a vmcnt wait that retires it — enforced by the ladder).
__device__ __forceinline__ short8 gload128(const unsigned short* p) {
    short8 r;
    asm volatile("global_load_dwordx4 %0, %1, off" : "=v"(r) : "v"(p) : "memory");
    return r;
}

__global__ void transpose_kernel(const float* __restrict__ src,
                                 unsigned short* __restrict__ dst,
                                 int K, int N, int ld) {
    int i = blockIdx.x * blockDim.x + threadIdx.x;
    if (i >= K * N) return;
    int n = i / K, k = i - n * K;
    dst[i] = f2bf(src[(size_t)k * ld + n]);
}

__global__ void bias_expand_kernel(const int* __restrict__ rel_index,
                                   const float* __restrict__ bias_table,
                                   float* __restrict__ biasx) {
    int i = blockIdx.x * blockDim.x + threadIdx.x;
    if (i >= NHEAD * 49 * 49) return;
    int h = i / 2401, r = i - h * 2401;
    biasx[i] = bias_table[rel_index[r] * NHEAD + h];
}

// LayerNorm over 384, fp32 in -> bf16 out; one wave per row.
__global__ __launch_bounds__(64) void ln_kernel(const float* __restrict__ x,
                                                const float* __restrict__ g,
                                                const float* __restrict__ b,
                                                unsigned short* __restrict__ out,
                                                int windowed) {
    int r = blockIdx.x;
    int lane = threadIdx.x;
    const float* row = x + (size_t)r * DIM;
    float v[6];
    float s = 0.f, ss = 0.f;
#pragma unroll
    for (int j = 0; j < 3; j++) {
        int c = lane + j * 64;
        float2 f = *(const float2*)(row + 2 * c);
        v[2 * j] = f.x; v[2 * j + 1] = f.y;
        s += f.x + f.y; ss += f.x * f.x + f.y * f.y;
    }
#pragma unroll
    for (int m = 1; m < 64; m <<= 1) {
        s += __shfl_xor(s, m);
        ss += __shfl_xor(ss, m);
    }
    float mean = s * (1.f / DIM);
    float var = ss * (1.f / DIM) - mean * mean;
    float rstd = rsqrtf(var + 1e-5f);
    int orow = windowed ? nat2win(r) : r;
    unsigned short* op = out + (size_t)orow * DIM;
#pragma unroll
    for (int j = 0; j < 3; j++) {
        int c = lane + j * 64;
        float2 gg = *(const float2*)(g + 2 * c);
        float2 bb = *(const float2*)(b + 2 * c);
        float o0 = (v[2 * j] - mean) * rstd * gg.x + bb.x;
        float o1 = (v[2 * j + 1] - mean) * rstd * gg.y + bb.y;
        unsigned int w = ((unsigned int)f2bf(o1) << 16) | f2bf(o0);
        *(unsigned int*)(op + 2 * c) = w;
    }
}

// MFMA attention: block = (image b, head h, group of 16 windows).
__global__ __launch_bounds__(256) void attn_kernel(const unsigned short* __restrict__ q,
                                                   const float* __restrict__ kv,
                                                   const float* __restrict__ biasx,
                                                   unsigned short* __restrict__ o) {
    __shared__ alignas(16) unsigned short Ks[64 * 40];   // [token][d] stride 40
    __shared__ alignas(16) unsigned short Vt[32 * 72];   // [d][token] stride 72
    __shared__ float Bi[49 * 52];                        // [qr][k] stride 52
    __shared__ alignas(16) unsigned short Ps[4][16 * 72];// per-wave P tile

    int blk = blockIdx.x;
    int b = blk / 48; int rem = blk - b * 48;
    int h = rem >> 2; int g = rem & 3;
    size_t row_base = (size_t)(b * 64 + g * 16) * 49;

    int t = threadIdx.x;
    int lane = t & 63;
    int wv = t >> 6;
    int lr = lane & 15;
    int lg = lane >> 4;

    const float* kptr = kv + (size_t)(b * NHEAD + h) * 1568;
    for (int idx = t; idx < 392; idx += 256) {
        int row = idx >> 3, seg = idx & 7;
        float4 f = *(const float4*)(kptr + row * 32 + seg * 4);
        ushort4 h4; h4.x = f2bf(f.x); h4.y = f2bf(f.y); h4.z = f2bf(f.z); h4.w = f2bf(f.w);
        *(ushort4*)&Ks[row * 40 + seg * 4] = h4;
    }
    const float* vptr = kv + (size_t)(192 + b * NHEAD + h) * 1568;
    for (int idx = t; idx < 784; idx += 256) {
        int m = idx >> 4, dp = idx & 15;
        float2 f = *(const float2*)(vptr + m * 32 + dp * 2);
        Vt[(2 * dp) * 72 + m]     = f2bf(f.x);
        Vt[(2 * dp + 1) * 72 + m] = f2bf(f.y);
    }
    for (int idx = t; idx < 32 * 23; idx += 256) {      // zero Vt token-pad 49..71
        int d = idx / 23, m = 49 + idx - d * 23;
        Vt[d * 72 + m] = 0;
    }
    const float* bh = biasx + h * 2401;
    for (int idx = t; idx < 2401; idx += 256) {
        int qr = idx / 49, k = idx - qr * 49;
        Bi[qr * 52 + k] = bh[idx];
    }
    __syncthreads();

    short8 bfr[4], vbf[2][2];
#pragma unroll
    for (int ni = 0; ni < 4; ni++)
        bfr[ni] = *(const short8*)&Ks[(ni * 16 + lr) * 40 + lg * 8];
#pragma unroll
    for (int ni = 0; ni < 2; ni++)
#pragma unroll
        for (int ks = 0; ks < 2; ks++)
            vbf[ni][ks] = *(const short8*)&Vt[(ni * 16 + lr) * 72 + ks * 32 + lg * 8];

    const unsigned short* qb = q + row_base * DIM + h * 32 + lg * 8;
    unsigned short* ob = o + row_base * DIM + h * 32;

    short8 af = *(const short8*)(qb + (size_t)(wv * 16 + lr) * DIM);
    for (int tm = wv; tm < 49; tm += 4) {
        short8 af_next;
        if (tm + 4 < 49) af_next = *(const short8*)(qb + (size_t)((tm + 4) * 16 + lr) * DIM);

        floatx4 sfrag[4];
#pragma unroll
        for (int ni = 0; ni < 4; ni++)
            sfrag[ni] = __builtin_amdgcn_mfma_f32_16x16x32_bf16(af, bfr[ni], (floatx4)0.f, 0, 0, 0);

#pragma unroll
        for (int reg = 0; reg < 4; reg++) {
            int r_loc = tm * 16 + lg * 4 + reg;
            int qr = r_loc % 49;
            float mx = -1e30f;
#pragma unroll
            for (int ni = 0; ni < 4; ni++) {
                int k = ni * 16 + lr;
                float s = sfrag[ni][reg];
                if (k < 49) s += Bi[qr * 52 + k];
                else s = -1e30f;
                sfrag[ni][reg] = s;
                mx = fmaxf(mx, s);
            }
#pragma unroll
            for (int j = 1; j < 16; j <<= 1) mx = fmaxf(mx, __shfl_xor(mx, j));
            float sum = 0.f;
#pragma unroll
            for (int ni = 0; ni < 4; ni++) {
                float e = __expf(sfrag[ni][reg] - mx);
                sfrag[ni][reg] = e;
                sum += e;
            }
#pragma unroll
            for (int j = 1; j < 16; j <<= 1) sum += __shfl_xor(sum, j);
            float inv = 1.f / sum;
#pragma unroll
            for (int ni = 0; ni < 4; ni++)
                Ps[wv][(lg * 4 + reg) * 72 + ni * 16 + lr] = f2bf(sfrag[ni][reg] * inv);
        }
        floatx4 ofrag[2] = {(floatx4)0.f, (floatx4)0.f};
#pragma unroll
        for (int ks = 0; ks < 2; ks++) {
            short8 paf = *(const short8*)&Ps[wv][lr * 72 + ks * 32 + lg * 8];
#pragma unroll
            for (int ni = 0; ni < 2; ni++)
                ofrag[ni] = __builtin_amdgcn_mfma_f32_16x16x32_bf16(paf, vbf[ni][ks], ofrag[ni], 0, 0, 0);
        }
#pragma unroll
        for (int reg = 0; reg < 4; reg++) {
            size_t rg = (size_t)(tm * 16 + lg * 4 + reg) * DIM;
#pragma unroll
            for (int ni = 0; ni < 2; ni++)
                ob[rg + ni * 16 + lr] = f2bf(ofrag[ni][reg]);
        }
        af = af_next;
    }
}

// Persistent-N GEMM v2: block = 128 rows x 384 cols (fc1: 1 of 4 col-chunks).
// A read ONCE into registers (asm gload, 2-step prefetch, never LDS-staged);
// B (L2-hot weights) streams through Bs[2][384x32] = 48 KB dbuf (2 blocks/CU,
// the measured rate-saturation point). Minimizes total staged bytes — the
// empirical limiter (time ~ staged bytes / 9.4 B/cyc/CU across R0-R10).
// 512 thr / 8 waves (4m x 2n); wave = 32 rows x 192 cols; acc[2][12] = 96 VGPR.
// One barrier/step; counted vmcnt(2) steady (retires B(kt)+A(kt), keeps next);
// asm ds_read groups of 3 + lgkmcnt(0) + sched_barrier (R8 discipline).
// Swizzle: phys chunk pc of row r holds global chunk pc ^ (r&3) ^ ((r>>2)&3);
// reader rows ≡ lr mod 16 -> same xr; 2-way bank alias only (free, m136).
#define BGROUP(G, A0, A1) do {                                                      \
    short8 b0 = ds_read128<(G) * 3072 + 0>(bB);                                     \
    short8 b1 = ds_read128<(G) * 3072 + 1024>(bB);                                  \
    short8 b2 = ds_read128<(G) * 3072 + 2048>(bB);                                  \
    asm volatile("s_waitcnt lgkmcnt(0)" ::: "memory");                              \
    __builtin_amdgcn_sched_barrier(0);                                              \
    acc[0][3*(G)+0] = __builtin_amdgcn_mfma_f32_16x16x32_bf16(A0, b0, acc[0][3*(G)+0], 0, 0, 0); \
    acc[1][3*(G)+0] = __builtin_amdgcn_mfma_f32_16x16x32_bf16(A1, b0, acc[1][3*(G)+0], 0, 0, 0); \
    acc[0][3*(G)+1] = __builtin_amdgcn_mfma_f32_16x16x32_bf16(A0, b1, acc[0][3*(G)+1], 0, 0, 0); \
    acc[1][3*(G)+1] = __builtin_amdgcn_mfma_f32_16x16x32_bf16(A1, b1, acc[1][3*(G)+1], 0, 0, 0); \
    acc[0][3*(G)+2] = __builtin_amdgcn_mfma_f32_16x16x32_bf16(A0, b2, acc[0][3*(G)+2], 0, 0, 0); \
    acc[1][3*(G)+2] = __builtin_amdgcn_mfma_f32_16x16x32_bf16(A1, b2, acc[1][3*(G)+2], 0, 0, 0); \
} while (0)

template <int DO_GELU, int DO_REMAP, int OUT_BF16>
__global__ __launch_bounds__(512) void gemm_kernel(const unsigned short* __restrict__ A,
                                                   const unsigned short* __restrict__ Bt,
                                                   const float* __restrict__ bias,
                                                   const float* __restrict__ res,
                                                   void* __restrict__ outv,
                                                   int Nstride, int K, float scale) {
    __shared__ alignas(16) unsigned short Bs[2][384 * 32];   // 48 KB

    int chunk = blockIdx.x;               // fc1 col-chunk (0..3); 0 elsewhere
    int m0 = blockIdx.y * 128;
    const unsigned short* Bc = Bt + (size_t)(chunk * 384) * K;
    int colbase = chunk * 384;

    int t = threadIdx.x;
    int lane = t & 63;
    int wv = t >> 6;                      // 0..7
    int wm = (wv >> 1) * 32;              // 4 m-waves x 32 rows
    int wn2 = (wv & 1) * 192;             // 2 n-waves x 192 cols
    int lr = lane & 15;
    int lq = lane >> 4;

    // reader swizzle (rows ≡ lr mod 16 for all accesses)
    int xrR = (lr & 3) ^ ((lr >> 2) & 3);
    u32 swB = (u32)((lq ^ xrR) << 4);     // byte offset within 64-byte row

    floatx4 acc[2][12];
#pragma unroll
    for (int m = 0; m < 2; m++)
#pragma unroll
        for (int n2 = 0; n2 < 12; n2++) acc[m][n2] = (floatx4)0.f;

    const unsigned short* Arow0 = A + (size_t)(m0 + wm + lr) * K + lq * 8;
    const unsigned short* Arow1 = Arow0 + (size_t)16 * K;

    // B staging: 1536 slots of 16B; thread t covers slots t, t+512, t+1024.
    auto stageB = [&](int buf, int kk) {
#pragma unroll
        for (int i = 0; i < 3; i++) {
            int s = i * 512 + t;
            int row = s >> 2;
            int gc = (s & 3) ^ ((row & 3) ^ ((row >> 2) & 3));
            GLOAD_LDS16(Bc + (size_t)row * K + kk + gc * 8, &Bs[buf][s * 8]);
        }
    };

    u32 bsBase = LDS_U32(&Bs[0][0]);
    u32 bRow = (u32)((wn2 + lr) * 64) + swB;

    const int nk = K >> 5;                // 12 or 48 (even)

    // ---- prologue: B0 [3], A(0)->X [2], A(1)->Y [2]  (7 in flight) ----
    stageB(0, 0);
    short8 aX0 = gload128(Arow0);
    short8 aX1 = gload128(Arow1);
    short8 aY0 = gload128(Arow0 + 32);
    short8 aY1 = gload128(Arow1 + 32);

    for (int kt = 0; kt < nk; kt += 2) {
        // ===== even step kt: Bs[0], X regs =====
        asm volatile("s_waitcnt vmcnt(2)" ::: "memory");   // retire B(kt)+A(kt)
        __builtin_amdgcn_s_barrier();
        stageB(1, (kt + 1) << 5);                          // kt+1 < nk always
        {
            u32 bB = bsBase + bRow;
            __builtin_amdgcn_s_setprio(1);
            BGROUP(0, aX0, aX1); BGROUP(1, aX0, aX1);
            BGROUP(2, aX0, aX1); BGROUP(3, aX0, aX1);
            __builtin_amdgcn_s_setprio(0);
        }
        if (kt + 2 < nk) {                                 // A(kt+2) -> X
            aX0 = gload128(Arow0 + (kt + 2) * 32);
            aX1 = gload128(Arow1 + (kt + 2) * 32);
        }
        // ===== odd step kt+1: Bs[1], Y regs =====
        if (kt + 2 < nk) asm volatile("s_waitcnt vmcnt(2)" ::: "memory");
        else             asm volatile("s_waitcnt vmcnt(0)" ::: "memory");
        __builtin_amdgcn_s_barrier();
        if (kt + 2 < nk) stageB(0, (kt + 2) << 5);
        {
            u32 bB = bsBase + 24576u + bRow;
            __builtin_amdgcn_s_setprio(1);
            BGROUP(0, aY0, aY1); BGROUP(1, aY0, aY1);
            BGROUP(2, aY0, aY1); BGROUP(3, aY0, aY1);
            __builtin_amdgcn_s_setprio(0);
        }
        if (kt + 3 < nk) {                                 // A(kt+3) -> Y
            aY0 = gload128(Arow0 + (kt + 3) * 32);
            aY1 = gload128(Arow1 + (kt + 3) * 32);
        }
    }

    // ---- epilogue (R6-verified layout) ----
#pragma unroll
    for (int n2 = 0; n2 < 12; n2++) {
        int gcol = colbase + wn2 + n2 * 16 + lr;
        float bv = bias[gcol];
#pragma unroll
        for (int m = 0; m < 2; m++) {
#pragma unroll
            for (int r = 0; r < 4; r++) {
                int grow = m0 + wm + m * 16 + lq * 4 + r;
                float val = acc[m][n2][r] + bv;
                if (DO_GELU) val = 0.5f * val * (1.f + erff(val * 0.70710678118654752f));
                val *= scale;
                int orow = DO_REMAP ? win2nat(grow) : grow;
                size_t idx = (size_t)orow * Nstride + gcol;
                if (res) val += res[idx];
                if (OUT_BF16) ((unsigned short*)outv)[idx] = f2bf(val);
                else          ((float*)outv)[idx] = val;
            }
        }
    }
}

extern "C" void kernel_launch(void* const* d_in, const int* in_sizes, int n_in,
                              void* d_out, int out_size, void* d_ws, size_t ws_size,
                              hipStream_t stream) {
    const float* x          = (const float*)d_in[0];
    const float* kv         = (const float*)d_in[1];
    const int*   rel_index  = (const int*)d_in[2];
    const float* g1         = (const float*)d_in[5];
    const float* b1         = (const float*)d_in[6];
    const float* Wqkv       = (const float*)d_in[7];
    const float* bqkv       = (const float*)d_in[8];
    const float* bias_table = (const float*)d_in[9];
    const float* Wproj      = (const float*)d_in[10];
    const float* bproj      = (const float*)d_in[11];
    const float* g2         = (const float*)d_in[12];
    const float* b2         = (const float*)d_in[13];
    const float* Wfc1       = (const float*)d_in[14];
    const float* bfc1       = (const float*)d_in[15];
    const float* Wfc2       = (const float*)d_in[16];
    const float* bfc2       = (const float*)d_in[17];
    float* out = (float*)d_out;

    char* ws = (char*)d_ws;
    unsigned short* wq_t   = (unsigned short*)(ws);
    unsigned short* wp_t   = (unsigned short*)(ws + 294912);
    unsigned short* wfc1_t = (unsigned short*)(ws + 589824);
    unsigned short* wfc2_t = (unsigned short*)(ws + 1769472);
    float*          biasx  = (float*)(ws + 2949120);
    unsigned short* bufA   = (unsigned short*)(ws + 3080192);
    unsigned short* bufB   = (unsigned short*)(ws + 3080192 + 38535168);

    const int M = 50176;
    const float scale = 0.17677669529663687f;
    const int full_mlp = (ws_size >= (size_t)3080192 + 38535168 + 154140672);

    transpose_kernel<<<(384 * 384 + 255) / 256, 256, 0, stream>>>(Wqkv, wq_t, 384, 384, 1152);
    transpose_kernel<<<(384 * 384 + 255) / 256, 256, 0, stream>>>(Wproj, wp_t, 384, 384, 384);
    transpose_kernel<<<(384 * 1536 + 255) / 256, 256, 0, stream>>>(Wfc1, wfc1_t, 384, 1536, 1536);
    transpose_kernel<<<(1536 * 384 + 255) / 256, 256, 0, stream>>>(Wfc2, wfc2_t, 1536, 384, 384);
    bias_expand_kernel<<<(NHEAD * 2401 + 255) / 256, 256, 0, stream>>>(rel_index, bias_table, biasx);

    // LN1 -> windowed (bf16)
    ln_kernel<<<M, 64, 0, stream>>>(x, g1, b1, bufA, 1);
    // q = (hw @ Wq + bq) * scale -> bufB
    gemm_kernel<0, 0, 1><<<dim3(1, M / 128), 512, 0, stream>>>(bufA, wq_t, bqkv, nullptr, bufB,
                                                               384, 384, scale);
    // attention -> bufA
    attn_kernel<<<16 * NHEAD * 4, 256, 0, stream>>>(bufB, kv, biasx, bufA);
    // proj + window_reverse + residual(x) -> d_out (fp32)
    gemm_kernel<0, 1, 0><<<dim3(1, M / 128), 512, 0, stream>>>(bufA, wp_t, bproj, x, d_out,
                                                               384, 384, 1.f);
    // LN2
    ln_kernel<<<M, 64, 0, stream>>>(out, g2, b2, bufA, 0);

    if (full_mlp) {
        gemm_kernel<1, 0, 1><<<dim3(4, M / 128), 512, 0, stream>>>(bufA, wfc1_t, bfc1,
                                                                   nullptr, bufB, 1536, 384, 1.f);
        gemm_kernel<0, 0, 0><<<dim3(1, M / 128), 512, 0, stream>>>(bufB, wfc2_t, bfc2,
                                                                   out, out, 384, 1536, 1.f);
    } else {
        for (int c = 0; c < 4; c++) {
            size_t ro = (size_t)c * 12544;
            gemm_kernel<1, 0, 1><<<dim3(4, 98), 512, 0, stream>>>(bufA + ro * 384, wfc1_t, bfc1,
                                                                  nullptr, bufB, 1536, 384, 1.f);
            gemm_kernel<0, 0, 0><<<dim3(1, 98), 512, 0, stream>>>(bufB, wfc2_t, bfc2,
                                                                  out + ro * 384, out + ro * 384,
                                                                  384, 1536, 1.f);
        }
    }
}

// Round 12
// 611.238 us; speedup vs baseline: 1.2384x; 1.2384x over previous
//
#include <hip/hip_runtime.h>

typedef __attribute__((ext_vector_type(8))) short short8;
typedef __attribute__((ext_vector_type(4))) float floatx4;
typedef unsigned int u32;

#define DIM 384
#define NHEAD 12
#define HDIM 32

__device__ __forceinline__ float bf2f(unsigned int u) {
    union { unsigned int i; float f; } x; x.i = (u & 0xffffu) << 16; return x.f;
}
__device__ __forceinline__ unsigned short f2bf(float f) {
    union { float f; unsigned int i; } x; x.f = f;
    return (unsigned short)((x.i + 0x7fffu + ((x.i >> 16) & 1u)) >> 16);
}

__device__ __forceinline__ int nat2win(int r) {
    int b = r / 3136; int l = r - b * 3136;
    int hh = l / 56, wc = l - hh * 56;
    int wh = hh / 7, nr = hh - wh * 7;
    int ww = wc / 7, nc = wc - ww * 7;
    return ((b << 6) + wh * 8 + ww) * 49 + nr * 7 + nc;
}
__device__ __forceinline__ int win2nat(int r) {
    int w = r / 49; int n = r - w * 49;
    int b = w >> 6; int wi = w & 63;
    int wh = wi >> 3, ww = wi & 7;
    int hh = wh * 7 + n / 7, wc = ww * 7 + n % 7;
    return b * 3136 + hh * 56 + wc;
}

#define GLOAD_LDS16(g, l) \
    __builtin_amdgcn_global_load_lds((const __attribute__((address_space(1))) u32*)(g), \
                                     (__attribute__((address_space(3))) u32*)(l), 16, 0, 0)

#define LDS_U32(p) ((u32)(uintptr_t)(__attribute__((address_space(3))) unsigned short*)(p))

// Opaque LDS read: compiler cannot connect this to global_load_lds writes,
// so it cannot insert its own vmcnt(0) drain — our counted waits are the
// only ordering (m201/m218 pattern; rule #18 fence applied at call sites).
template <int OFF>
__device__ __forceinline__ short8 ds_read128(u32 addr) {
    short8 r;
    asm volatile("ds_read_b128 %0, %1 offset:%2" : "=v"(r) : "v"(addr), "i"(OFF));
    return r;
}

// Merged preprocessing: 4 weight transposes (fp32 -> bf16, N-major) + bias
// expansion, one dispatch instead of five. Segment layout:
//   [0,147456)        wq_t  : dst[n*384+k]  = Wqkv[k*1152+n]
//   [147456,294912)   wp_t  : dst[n*384+k]  = Wproj[k*384+n]
//   [294912,884736)   wfc1_t: dst[n*384+k]  = Wfc1[k*1536+n]
//   [884736,1474560)  wfc2_t: dst[n*1536+k] = Wfc2[k*384+n]
//   [1474560,1503372) biasx : [h*2401+r]    = bias_table[rel_index[r]*12+h]
__global__ void prep_kernel(const float* __restrict__ Wqkv,
                            const float* __restrict__ Wproj,
                            const float* __restrict__ Wfc1,
                            const float* __restrict__ Wfc2,
                            const int* __restrict__ rel_index,
                            const float* __restrict__ bias_table,
                            unsigned short* __restrict__ wq_t,
                            unsigned short* __restrict__ wp_t,
                            unsigned short* __restrict__ wfc1_t,
                            unsigned short* __restrict__ wfc2_t,
                            float* __restrict__ biasx) {
    int i = blockIdx.x * blockDim.x + threadIdx.x;
    if (i < 147456) {
        int n = i / 384, k = i - n * 384;
        wq_t[i] = f2bf(Wqkv[(size_t)k * 1152 + n]);
        return;
    }
    i -= 147456;
    if (i < 147456) {
        int n = i / 384, k = i - n * 384;
        wp_t[i] = f2bf(Wproj[(size_t)k * 384 + n]);
        return;
    }
    i -= 147456;
    if (i < 589824) {
        int n = i / 384, k = i - n * 384;
        wfc1_t[i] = f2bf(Wfc1[(size_t)k * 1536 + n]);
        return;
    }
    i -= 589824;
    if (i < 589824) {
        int n = i / 1536, k = i - n * 1536;
        wfc2_t[i] = f2bf(Wfc2[(size_t)k * 384 + n]);
        return;
    }
    i -= 589824;
    if (i < 28812) {
        int h = i / 2401, r = i - h * 2401;
        biasx[i] = bias_table[rel_index[r] * NHEAD + h];
    }
}

// LayerNorm over 384, fp32 in -> bf16 out; one wave per row.
__global__ __launch_bounds__(64) void ln_kernel(const float* __restrict__ x,
                                                const float* __restrict__ g,
                                                const float* __restrict__ b,
                                                unsigned short* __restrict__ out,
                                                int windowed) {
    int r = blockIdx.x;
    int lane = threadIdx.x;
    const float* row = x + (size_t)r * DIM;
    float v[6];
    float s = 0.f, ss = 0.f;
#pragma unroll
    for (int j = 0; j < 3; j++) {
        int c = lane + j * 64;
        float2 f = *(const float2*)(row + 2 * c);
        v[2 * j] = f.x; v[2 * j + 1] = f.y;
        s += f.x + f.y; ss += f.x * f.x + f.y * f.y;
    }
#pragma unroll
    for (int m = 1; m < 64; m <<= 1) {
        s += __shfl_xor(s, m);
        ss += __shfl_xor(ss, m);
    }
    float mean = s * (1.f / DIM);
    float var = ss * (1.f / DIM) - mean * mean;
    float rstd = rsqrtf(var + 1e-5f);
    int orow = windowed ? nat2win(r) : r;
    unsigned short* op = out + (size_t)orow * DIM;
#pragma unroll
    for (int j = 0; j < 3; j++) {
        int c = lane + j * 64;
        float2 gg = *(const float2*)(g + 2 * c);
        float2 bb = *(const float2*)(b + 2 * c);
        float o0 = (v[2 * j] - mean) * rstd * gg.x + bb.x;
        float o1 = (v[2 * j + 1] - mean) * rstd * gg.y + bb.y;
        unsigned int w = ((unsigned int)f2bf(o1) << 16) | f2bf(o0);
        *(unsigned int*)(op + 2 * c) = w;
    }
}

// MFMA attention: block = (image b, head h, group of 16 windows).
__global__ __launch_bounds__(256) void attn_kernel(const unsigned short* __restrict__ q,
                                                   const float* __restrict__ kv,
                                                   const float* __restrict__ biasx,
                                                   unsigned short* __restrict__ o) {
    __shared__ alignas(16) unsigned short Ks[64 * 40];   // [token][d] stride 40
    __shared__ alignas(16) unsigned short Vt[32 * 72];   // [d][token] stride 72
    __shared__ float Bi[49 * 52];                        // [qr][k] stride 52
    __shared__ alignas(16) unsigned short Ps[4][16 * 72];// per-wave P tile

    int blk = blockIdx.x;
    int b = blk / 48; int rem = blk - b * 48;
    int h = rem >> 2; int g = rem & 3;
    size_t row_base = (size_t)(b * 64 + g * 16) * 49;

    int t = threadIdx.x;
    int lane = t & 63;
    int wv = t >> 6;
    int lr = lane & 15;
    int lg = lane >> 4;

    const float* kptr = kv + (size_t)(b * NHEAD + h) * 1568;
    for (int idx = t; idx < 392; idx += 256) {
        int row = idx >> 3, seg = idx & 7;
        float4 f = *(const float4*)(kptr + row * 32 + seg * 4);
        ushort4 h4; h4.x = f2bf(f.x); h4.y = f2bf(f.y); h4.z = f2bf(f.z); h4.w = f2bf(f.w);
        *(ushort4*)&Ks[row * 40 + seg * 4] = h4;
    }
    const float* vptr = kv + (size_t)(192 + b * NHEAD + h) * 1568;
    for (int idx = t; idx < 784; idx += 256) {
        int m = idx >> 4, dp = idx & 15;
        float2 f = *(const float2*)(vptr + m * 32 + dp * 2);
        Vt[(2 * dp) * 72 + m]     = f2bf(f.x);
        Vt[(2 * dp + 1) * 72 + m] = f2bf(f.y);
    }
    for (int idx = t; idx < 32 * 23; idx += 256) {      // zero Vt token-pad 49..71
        int d = idx / 23, m = 49 + idx - d * 23;
        Vt[d * 72 + m] = 0;
    }
    const float* bh = biasx + h * 2401;
    for (int idx = t; idx < 2401; idx += 256) {
        int qr = idx / 49, k = idx - qr * 49;
        Bi[qr * 52 + k] = bh[idx];
    }
    __syncthreads();

    short8 bfr[4], vbf[2][2];
#pragma unroll
    for (int ni = 0; ni < 4; ni++)
        bfr[ni] = *(const short8*)&Ks[(ni * 16 + lr) * 40 + lg * 8];
#pragma unroll
    for (int ni = 0; ni < 2; ni++)
#pragma unroll
        for (int ks = 0; ks < 2; ks++)
            vbf[ni][ks] = *(const short8*)&Vt[(ni * 16 + lr) * 72 + ks * 32 + lg * 8];

    const unsigned short* qb = q + row_base * DIM + h * 32 + lg * 8;
    unsigned short* ob = o + row_base * DIM + h * 32;

    short8 af = *(const short8*)(qb + (size_t)(wv * 16 + lr) * DIM);
    for (int tm = wv; tm < 49; tm += 4) {
        short8 af_next;
        if (tm + 4 < 49) af_next = *(const short8*)(qb + (size_t)((tm + 4) * 16 + lr) * DIM);

        floatx4 sfrag[4];
#pragma unroll
        for (int ni = 0; ni < 4; ni++)
            sfrag[ni] = __builtin_amdgcn_mfma_f32_16x16x32_bf16(af, bfr[ni], (floatx4)0.f, 0, 0, 0);

#pragma unroll
        for (int reg = 0; reg < 4; reg++) {
            int r_loc = tm * 16 + lg * 4 + reg;
            int qr = r_loc % 49;
            float mx = -1e30f;
#pragma unroll
            for (int ni = 0; ni < 4; ni++) {
                int k = ni * 16 + lr;
                float s = sfrag[ni][reg];
                if (k < 49) s += Bi[qr * 52 + k];
                else s = -1e30f;
                sfrag[ni][reg] = s;
                mx = fmaxf(mx, s);
            }
#pragma unroll
            for (int j = 1; j < 16; j <<= 1) mx = fmaxf(mx, __shfl_xor(mx, j));
            float sum = 0.f;
#pragma unroll
            for (int ni = 0; ni < 4; ni++) {
                float e = __expf(sfrag[ni][reg] - mx);
                sfrag[ni][reg] = e;
                sum += e;
            }
#pragma unroll
            for (int j = 1; j < 16; j <<= 1) sum += __shfl_xor(sum, j);
            float inv = 1.f / sum;
#pragma unroll
            for (int ni = 0; ni < 4; ni++)
                Ps[wv][(lg * 4 + reg) * 72 + ni * 16 + lr] = f2bf(sfrag[ni][reg] * inv);
        }
        floatx4 ofrag[2] = {(floatx4)0.f, (floatx4)0.f};
#pragma unroll
        for (int ks = 0; ks < 2; ks++) {
            short8 paf = *(const short8*)&Ps[wv][lr * 72 + ks * 32 + lg * 8];
#pragma unroll
            for (int ni = 0; ni < 2; ni++)
                ofrag[ni] = __builtin_amdgcn_mfma_f32_16x16x32_bf16(paf, vbf[ni][ks], ofrag[ni], 0, 0, 0);
        }
#pragma unroll
        for (int reg = 0; reg < 4; reg++) {
            size_t rg = (size_t)(tm * 16 + lg * 4 + reg) * DIM;
#pragma unroll
            for (int ni = 0; ni < 2; ni++)
                ob[rg + ni * 16 + lr] = f2bf(ofrag[ni][reg]);
        }
        af = af_next;
    }
}

// C[M,N] = A[M,K](bf16) @ Bt[N,K](bf16)^T ; 128x128 tile, BK=64, XOR swizzle.
// R8 (best measured): As[3] (A staged 2 iterations ahead), Bs[2] (B 1 ahead),
// ONE barrier per K-tile after counted vmcnt(4); staging issued right after
// the barrier into buffers disjoint from those being read; fragment loads via
// opaque inline-asm ds_read_b128 so the compiler cannot insert its own
// vmcnt(0) drain (the mechanism that nullified rounds 0-7). Read discipline
// per rule #18: 16 asm reads -> lgkmcnt(8)+sched_barrier -> 16 MFMA ->
// lgkmcnt(0)+sched_barrier -> 16 MFMA.
template <int DO_GELU, int DO_REMAP, int OUT_BF16>
__global__ __launch_bounds__(256) void gemm_kernel(const unsigned short* __restrict__ A,
                                                   const unsigned short* __restrict__ Bt,
                                                   const float* __restrict__ bias,
                                                   const float* __restrict__ res,
                                                   void* __restrict__ outv,
                                                   int M, int N, int K, float scale) {
    __shared__ alignas(16) unsigned short As[3][128 * 64];
    __shared__ alignas(16) unsigned short Bs[2][128 * 64];

    // bijective XCD swizzle (m204)
    int nwg = gridDim.x * gridDim.y;
    int lid = blockIdx.y * gridDim.x + blockIdx.x;
    int q8 = nwg >> 3, r8 = nwg & 7;
    int xcd = lid & 7, pos = lid >> 3;
    int nlid = (xcd < r8 ? xcd * (q8 + 1) : r8 * (q8 + 1) + (xcd - r8) * q8) + pos;
    int m0 = (nlid / gridDim.x) * 128;
    int n0 = (nlid % gridDim.x) * 128;

    int t = threadIdx.x;
    int lane = t & 63;
    int wv = t >> 6;
    int wm = (wv >> 1) * 64, wn = (wv & 1) * 64;
    int lr = lane & 15;
    int lq = lane >> 4;

    // staging map: slot s = i*256+t holds global (row = s>>3, chunk = (s&7)^(row&7))
    int rowB = t >> 3;
    int colOff = (((t & 7) ^ ((t >> 3) & 7)) << 3);   // shorts
    // reader swizzle: chunk c stored at (c ^ (lr&7))
    int sw0 = ((lq ^ (lr & 7)) << 3);
    int sw1 = (((4 + lq) ^ (lr & 7)) << 3);

    floatx4 acc[4][4];
#pragma unroll
    for (int i = 0; i < 4; i++)
#pragma unroll
        for (int j = 0; j < 4; j++) acc[i][j] = (floatx4)0.f;

    const unsigned short* Abase = A + (size_t)(m0 + rowB) * K + colOff;
    const unsigned short* Bbase = Bt + (size_t)(n0 + rowB) * K + colOff;
    size_t rstep = (size_t)32 * K;

    auto stageA = [&](int buf, int kk) {
#pragma unroll
        for (int i = 0; i < 4; i++)
            GLOAD_LDS16(Abase + (size_t)i * rstep + kk, &As[buf][(i * 256 + t) * 8]);
    };
    auto stageB = [&](int buf, int kk) {
#pragma unroll
        for (int i = 0; i < 4; i++)
            GLOAD_LDS16(Bbase + (size_t)i * rstep + kk, &Bs[buf][(i * 256 + t) * 8]);
    };

    // LDS byte bases for opaque reads
    u32 asBase = LDS_U32(&As[0][0]);
    u32 bsBase = LDS_U32(&Bs[0][0]);
    u32 aRow = (u32)(((wm + lr) * 64) << 1);   // byte offset of this lane's A row
    u32 bRow = (u32)(((wn + lr) * 64) << 1);

    const int nk = K >> 6;          // >= 6 at all call sites

    // ---- prologue: B0, A0, A1 (12 loads in flight) ----
    stageB(0, 0);
    stageA(0, 0);
    stageA(1, 64);

    for (int kt = 0; kt < nk; ++kt) {
        int ab = kt % 3;
        int bb = kt & 1;
        // retire A(kt)+B(kt); keep A(kt+1)'s 4 loads in flight
        if (kt + 1 < nk) asm volatile("s_waitcnt vmcnt(4)" ::: "memory");
        else             asm volatile("s_waitcnt vmcnt(0)" ::: "memory");
        __builtin_amdgcn_s_barrier();            // tile kt visible to all waves
        // issue next staging FIRST (2-ahead for A, 1-ahead for B), then compute
        if (kt + 1 < nk) stageB(bb ^ 1, (kt + 1) << 6);
        if (kt + 2 < nk) stageA((kt + 2) % 3, (kt + 2) << 6);

        u32 aB0 = asBase + (u32)ab * 16384u + aRow + ((u32)sw0 << 1);
        u32 aB1 = asBase + (u32)ab * 16384u + aRow + ((u32)sw1 << 1);
        u32 bB0 = bsBase + (u32)bb * 16384u + bRow + ((u32)sw0 << 1);
        u32 bB1 = bsBase + (u32)bb * 16384u + bRow + ((u32)sw1 << 1);

        short8 a0[4], b0[4], a1[4], b1[4];
        a0[0] = ds_read128<0>(aB0);    a0[1] = ds_read128<2048>(aB0);
        a0[2] = ds_read128<4096>(aB0); a0[3] = ds_read128<6144>(aB0);
        b0[0] = ds_read128<0>(bB0);    b0[1] = ds_read128<2048>(bB0);
        b0[2] = ds_read128<4096>(bB0); b0[3] = ds_read128<6144>(bB0);
        a1[0] = ds_read128<0>(aB1);    a1[1] = ds_read128<2048>(aB1);
        a1[2] = ds_read128<4096>(aB1); a1[3] = ds_read128<6144>(aB1);
        b1[0] = ds_read128<0>(bB1);    b1[1] = ds_read128<2048>(bB1);
        b1[2] = ds_read128<4096>(bB1); b1[3] = ds_read128<6144>(bB1);

        asm volatile("s_waitcnt lgkmcnt(8)" ::: "memory");   // ksub0's 8 reads done
        __builtin_amdgcn_sched_barrier(0);                   // rule #18 fence
        __builtin_amdgcn_s_setprio(1);
#pragma unroll
        for (int i = 0; i < 4; i++)
#pragma unroll
            for (int j = 0; j < 4; j++)
                acc[i][j] = __builtin_amdgcn_mfma_f32_16x16x32_bf16(a0[i], b0[j], acc[i][j], 0, 0, 0);
        asm volatile("s_waitcnt lgkmcnt(0)" ::: "memory");   // ksub1's reads done
        __builtin_amdgcn_sched_barrier(0);
#pragma unroll
        for (int i = 0; i < 4; i++)
#pragma unroll
            for (int j = 0; j < 4; j++)
                acc[i][j] = __builtin_amdgcn_mfma_f32_16x16x32_bf16(a1[i], b1[j], acc[i][j], 0, 0, 0);
        __builtin_amdgcn_s_setprio(0);
        // no trailing barrier: staging targets buffers disjoint from those
        // being read this iteration; top barrier bounds wave skew (R7 audit).
    }

#pragma unroll
    for (int j = 0; j < 4; j++) {
        int gcol = n0 + wn + j * 16 + lr;
        float bv = bias[gcol];
#pragma unroll
        for (int i = 0; i < 4; i++) {
#pragma unroll
            for (int r = 0; r < 4; r++) {
                int grow = m0 + wm + i * 16 + lq * 4 + r;
                float val = acc[i][j][r] + bv;
                if (DO_GELU) val = 0.5f * val * (1.f + erff(val * 0.70710678118654752f));
                val *= scale;
                int orow = DO_REMAP ? win2nat(grow) : grow;
                size_t idx = (size_t)orow * N + gcol;
                if (res) val += res[idx];
                if (OUT_BF16) ((unsigned short*)outv)[idx] = f2bf(val);
                else          ((float*)outv)[idx] = val;
            }
        }
    }
}

extern "C" void kernel_launch(void* const* d_in, const int* in_sizes, int n_in,
                              void* d_out, int out_size, void* d_ws, size_t ws_size,
                              hipStream_t stream) {
    const float* x          = (const float*)d_in[0];
    const float* kv         = (const float*)d_in[1];
    const int*   rel_index  = (const int*)d_in[2];
    const float* g1         = (const float*)d_in[5];
    const float* b1         = (const float*)d_in[6];
    const float* Wqkv       = (const float*)d_in[7];
    const float* bqkv       = (const float*)d_in[8];
    const float* bias_table = (const float*)d_in[9];
    const float* Wproj      = (const float*)d_in[10];
    const float* bproj      = (const float*)d_in[11];
    const float* g2         = (const float*)d_in[12];
    const float* b2         = (const float*)d_in[13];
    const float* Wfc1       = (const float*)d_in[14];
    const float* bfc1       = (const float*)d_in[15];
    const float* Wfc2       = (const float*)d_in[16];
    const float* bfc2       = (const float*)d_in[17];
    float* out = (float*)d_out;

    char* ws = (char*)d_ws;
    unsigned short* wq_t   = (unsigned short*)(ws);
    unsigned short* wp_t   = (unsigned short*)(ws + 294912);
    unsigned short* wfc1_t = (unsigned short*)(ws + 589824);
    unsigned short* wfc2_t = (unsigned short*)(ws + 1769472);
    float*          biasx  = (float*)(ws + 2949120);
    unsigned short* bufA   = (unsigned short*)(ws + 3080192);
    unsigned short* bufB   = (unsigned short*)(ws + 3080192 + 38535168);

    const int M = 50176;
    const float scale = 0.17677669529663687f;
    const int full_mlp = (ws_size >= (size_t)3080192 + 38535168 + 154140672);

    // merged preprocessing: 4 transposes + bias expand in ONE dispatch
    prep_kernel<<<(1503372 + 255) / 256, 256, 0, stream>>>(Wqkv, Wproj, Wfc1, Wfc2,
                                                           rel_index, bias_table,
                                                           wq_t, wp_t, wfc1_t, wfc2_t, biasx);

    // LN1 -> windowed (bf16)
    ln_kernel<<<M, 64, 0, stream>>>(x, g1, b1, bufA, 1);
    // q = (hw @ Wq + bq) * scale -> bufB
    gemm_kernel<0, 0, 1><<<dim3(3, 392), 256, 0, stream>>>(bufA, wq_t, bqkv, nullptr, bufB,
                                                           M, 384, 384, scale);
    // attention -> bufA
    attn_kernel<<<16 * NHEAD * 4, 256, 0, stream>>>(bufB, kv, biasx, bufA);
    // proj + window_reverse + residual(x) -> d_out (fp32)
    gemm_kernel<0, 1, 0><<<dim3(3, 392), 256, 0, stream>>>(bufA, wp_t, bproj, x, d_out,
                                                           M, 384, 384, 1.f);
    // LN2
    ln_kernel<<<M, 64, 0, stream>>>(out, g2, b2, bufA, 0);

    if (full_mlp) {
        gemm_kernel<1, 0, 1><<<dim3(12, 392), 256, 0, stream>>>(bufA, wfc1_t, bfc1,
                                                                nullptr, bufB, M, 1536, 384, 1.f);
        gemm_kernel<0, 0, 0><<<dim3(3, 392), 256, 0, stream>>>(bufB, wfc2_t, bfc2,
                                                               out, out, M, 384, 1536, 1.f);
    } else {
        for (int c = 0; c < 4; c++) {
            size_t ro = (size_t)c * 12544;
            gemm_kernel<1, 0, 1><<<dim3(12, 98), 256, 0, stream>>>(bufA + ro * 384, wfc1_t, bfc1,
                                                                   nullptr, bufB, 12544, 1536, 384, 1.f);
            gemm_kernel<0, 0, 0><<<dim3(3, 98), 256, 0, stream>>>(bufB, wfc2_t, bfc2,
                                                                  out + ro * 384, out + ro * 384,
                                                                  12544, 384, 1536, 1.f);
        }
    }
}

// Round 13
// 603.367 us; speedup vs baseline: 1.2546x; 1.0130x over previous
//
#include <hip/hip_runtime.h>

typedef __attribute__((ext_vector_type(8))) short short8;
typedef __attribute__((ext_vector_type(4))) float floatx4;
typedef unsigned int u32;

#define DIM 384
#define NHEAD 12
#define HDIM 32

__device__ __forceinline__ float bf2f(unsigned int u) {
    union { unsigned int i; float f; } x; x.i = (u & 0xffffu) << 16; return x.f;
}
__device__ __forceinline__ unsigned short f2bf(float f) {
    union { float f; unsigned int i; } x; x.f = f;
    return (unsigned short)((x.i + 0x7fffu + ((x.i >> 16) & 1u)) >> 16);
}

__device__ __forceinline__ int nat2win(int r) {
    int b = r / 3136; int l = r - b * 3136;
    int hh = l / 56, wc = l - hh * 56;
    int wh = hh / 7, nr = hh - wh * 7;
    int ww = wc / 7, nc = wc - ww * 7;
    return ((b << 6) + wh * 8 + ww) * 49 + nr * 7 + nc;
}
__device__ __forceinline__ int win2nat(int r) {
    int w = r / 49; int n = r - w * 49;
    int b = w >> 6; int wi = w & 63;
    int wh = wi >> 3, ww = wi & 7;
    int hh = wh * 7 + n / 7, wc = ww * 7 + n % 7;
    return b * 3136 + hh * 56 + wc;
}

#define GLOAD_LDS16(g, l) \
    __builtin_amdgcn_global_load_lds((const __attribute__((address_space(1))) u32*)(g), \
                                     (__attribute__((address_space(3))) u32*)(l), 16, 0, 0)

#define LDS_U32(p) ((u32)(uintptr_t)(__attribute__((address_space(3))) unsigned short*)(p))

// Opaque LDS read: compiler cannot connect this to global_load_lds writes,
// so it cannot insert its own vmcnt(0) drain — our counted waits are the
// only ordering (m201/m218 pattern; rule #18 fence applied at call sites).
template <int OFF>
__device__ __forceinline__ short8 ds_read128(u32 addr) {
    short8 r;
    asm volatile("ds_read_b128 %0, %1 offset:%2" : "=v"(r) : "v"(addr), "i"(OFF));
    return r;
}

// Merged preprocessing: 4 weight transposes (fp32 -> bf16, N-major) + bias
// expansion, one dispatch instead of five.
__global__ void prep_kernel(const float* __restrict__ Wqkv,
                            const float* __restrict__ Wproj,
                            const float* __restrict__ Wfc1,
                            const float* __restrict__ Wfc2,
                            const int* __restrict__ rel_index,
                            const float* __restrict__ bias_table,
                            unsigned short* __restrict__ wq_t,
                            unsigned short* __restrict__ wp_t,
                            unsigned short* __restrict__ wfc1_t,
                            unsigned short* __restrict__ wfc2_t,
                            float* __restrict__ biasx) {
    int i = blockIdx.x * blockDim.x + threadIdx.x;
    if (i < 147456) {
        int n = i / 384, k = i - n * 384;
        wq_t[i] = f2bf(Wqkv[(size_t)k * 1152 + n]);
        return;
    }
    i -= 147456;
    if (i < 147456) {
        int n = i / 384, k = i - n * 384;
        wp_t[i] = f2bf(Wproj[(size_t)k * 384 + n]);
        return;
    }
    i -= 147456;
    if (i < 589824) {
        int n = i / 384, k = i - n * 384;
        wfc1_t[i] = f2bf(Wfc1[(size_t)k * 1536 + n]);
        return;
    }
    i -= 589824;
    if (i < 589824) {
        int n = i / 1536, k = i - n * 1536;
        wfc2_t[i] = f2bf(Wfc2[(size_t)k * 384 + n]);
        return;
    }
    i -= 589824;
    if (i < 28812) {
        int h = i / 2401, r = i - h * 2401;
        biasx[i] = bias_table[rel_index[r] * NHEAD + h];
    }
}

// LayerNorm over 384, fp32 in -> bf16 out; one wave per row.
__global__ __launch_bounds__(64) void ln_kernel(const float* __restrict__ x,
                                                const float* __restrict__ g,
                                                const float* __restrict__ b,
                                                unsigned short* __restrict__ out,
                                                int windowed) {
    int r = blockIdx.x;
    int lane = threadIdx.x;
    const float* row = x + (size_t)r * DIM;
    float v[6];
    float s = 0.f, ss = 0.f;
#pragma unroll
    for (int j = 0; j < 3; j++) {
        int c = lane + j * 64;
        float2 f = *(const float2*)(row + 2 * c);
        v[2 * j] = f.x; v[2 * j + 1] = f.y;
        s += f.x + f.y; ss += f.x * f.x + f.y * f.y;
    }
#pragma unroll
    for (int m = 1; m < 64; m <<= 1) {
        s += __shfl_xor(s, m);
        ss += __shfl_xor(ss, m);
    }
    float mean = s * (1.f / DIM);
    float var = ss * (1.f / DIM) - mean * mean;
    float rstd = rsqrtf(var + 1e-5f);
    int orow = windowed ? nat2win(r) : r;
    unsigned short* op = out + (size_t)orow * DIM;
#pragma unroll
    for (int j = 0; j < 3; j++) {
        int c = lane + j * 64;
        float2 gg = *(const float2*)(g + 2 * c);
        float2 bb = *(const float2*)(b + 2 * c);
        float o0 = (v[2 * j] - mean) * rstd * gg.x + bb.x;
        float o1 = (v[2 * j + 1] - mean) * rstd * gg.y + bb.y;
        unsigned int w = ((unsigned int)f2bf(o1) << 16) | f2bf(o0);
        *(unsigned int*)(op + 2 * c) = w;
    }
}

// MFMA attention: block = (image b, head h, group of 16 windows).
__global__ __launch_bounds__(256) void attn_kernel(const unsigned short* __restrict__ q,
                                                   const float* __restrict__ kv,
                                                   const float* __restrict__ biasx,
                                                   unsigned short* __restrict__ o) {
    __shared__ alignas(16) unsigned short Ks[64 * 40];   // [token][d] stride 40
    __shared__ alignas(16) unsigned short Vt[32 * 72];   // [d][token] stride 72
    __shared__ float Bi[49 * 52];                        // [qr][k] stride 52
    __shared__ alignas(16) unsigned short Ps[4][16 * 72];// per-wave P tile

    int blk = blockIdx.x;
    int b = blk / 48; int rem = blk - b * 48;
    int h = rem >> 2; int g = rem & 3;
    size_t row_base = (size_t)(b * 64 + g * 16) * 49;

    int t = threadIdx.x;
    int lane = t & 63;
    int wv = t >> 6;
    int lr = lane & 15;
    int lg = lane >> 4;

    const float* kptr = kv + (size_t)(b * NHEAD + h) * 1568;
    for (int idx = t; idx < 392; idx += 256) {
        int row = idx >> 3, seg = idx & 7;
        float4 f = *(const float4*)(kptr + row * 32 + seg * 4);
        ushort4 h4; h4.x = f2bf(f.x); h4.y = f2bf(f.y); h4.z = f2bf(f.z); h4.w = f2bf(f.w);
        *(ushort4*)&Ks[row * 40 + seg * 4] = h4;
    }
    const float* vptr = kv + (size_t)(192 + b * NHEAD + h) * 1568;
    for (int idx = t; idx < 784; idx += 256) {
        int m = idx >> 4, dp = idx & 15;
        float2 f = *(const float2*)(vptr + m * 32 + dp * 2);
        Vt[(2 * dp) * 72 + m]     = f2bf(f.x);
        Vt[(2 * dp + 1) * 72 + m] = f2bf(f.y);
    }
    for (int idx = t; idx < 32 * 23; idx += 256) {      // zero Vt token-pad 49..71
        int d = idx / 23, m = 49 + idx - d * 23;
        Vt[d * 72 + m] = 0;
    }
    const float* bh = biasx + h * 2401;
    for (int idx = t; idx < 2401; idx += 256) {
        int qr = idx / 49, k = idx - qr * 49;
        Bi[qr * 52 + k] = bh[idx];
    }
    __syncthreads();

    short8 bfr[4], vbf[2][2];
#pragma unroll
    for (int ni = 0; ni < 4; ni++)
        bfr[ni] = *(const short8*)&Ks[(ni * 16 + lr) * 40 + lg * 8];
#pragma unroll
    for (int ni = 0; ni < 2; ni++)
#pragma unroll
        for (int ks = 0; ks < 2; ks++)
            vbf[ni][ks] = *(const short8*)&Vt[(ni * 16 + lr) * 72 + ks * 32 + lg * 8];

    const unsigned short* qb = q + row_base * DIM + h * 32 + lg * 8;
    unsigned short* ob = o + row_base * DIM + h * 32;

    short8 af = *(const short8*)(qb + (size_t)(wv * 16 + lr) * DIM);
    for (int tm = wv; tm < 49; tm += 4) {
        short8 af_next;
        if (tm + 4 < 49) af_next = *(const short8*)(qb + (size_t)((tm + 4) * 16 + lr) * DIM);

        floatx4 sfrag[4];
#pragma unroll
        for (int ni = 0; ni < 4; ni++)
            sfrag[ni] = __builtin_amdgcn_mfma_f32_16x16x32_bf16(af, bfr[ni], (floatx4)0.f, 0, 0, 0);

#pragma unroll
        for (int reg = 0; reg < 4; reg++) {
            int r_loc = tm * 16 + lg * 4 + reg;
            int qr = r_loc % 49;
            float mx = -1e30f;
#pragma unroll
            for (int ni = 0; ni < 4; ni++) {
                int k = ni * 16 + lr;
                float s = sfrag[ni][reg];
                if (k < 49) s += Bi[qr * 52 + k];
                else s = -1e30f;
                sfrag[ni][reg] = s;
                mx = fmaxf(mx, s);
            }
#pragma unroll
            for (int j = 1; j < 16; j <<= 1) mx = fmaxf(mx, __shfl_xor(mx, j));
            float sum = 0.f;
#pragma unroll
            for (int ni = 0; ni < 4; ni++) {
                float e = __expf(sfrag[ni][reg] - mx);
                sfrag[ni][reg] = e;
                sum += e;
            }
#pragma unroll
            for (int j = 1; j < 16; j <<= 1) sum += __shfl_xor(sum, j);
            float inv = 1.f / sum;
#pragma unroll
            for (int ni = 0; ni < 4; ni++)
                Ps[wv][(lg * 4 + reg) * 72 + ni * 16 + lr] = f2bf(sfrag[ni][reg] * inv);
        }
        floatx4 ofrag[2] = {(floatx4)0.f, (floatx4)0.f};
#pragma unroll
        for (int ks = 0; ks < 2; ks++) {
            short8 paf = *(const short8*)&Ps[wv][lr * 72 + ks * 32 + lg * 8];
#pragma unroll
            for (int ni = 0; ni < 2; ni++)
                ofrag[ni] = __builtin_amdgcn_mfma_f32_16x16x32_bf16(paf, vbf[ni][ks], ofrag[ni], 0, 0, 0);
        }
#pragma unroll
        for (int reg = 0; reg < 4; reg++) {
            size_t rg = (size_t)(tm * 16 + lg * 4 + reg) * DIM;
#pragma unroll
            for (int ni = 0; ni < 2; ni++)
                ob[rg + ni * 16 + lr] = f2bf(ofrag[ni][reg]);
        }
        af = af_next;
    }
}

// C[M,N] = A[M,K](bf16) @ Bt[N,K](bf16)^T ; 256x128 tile, BK=32, 512 threads.
// Staged-bytes reduction on the validated R8 skeleton: As[3](48KB, A staged
// 2 iters ahead) + Bs[2](16KB, B 1 ahead) = 64 KB -> 2 blocks/CU (the
// measured DMA-rate saturation point) while cutting staged bytes 25-28%
// (A-panel re-staging drops with the taller tile). 8 waves = 4m x 2n, each
// wave 64x64 out — identical fragment math / acc[4][4] as R8. One barrier
// per K-step after counted vmcnt; opaque asm ds_read_b128 + lgkmcnt(0) +
// sched_barrier (rule #18). Swizzle: R10's refcheck-passed involution for
// 4-chunk rows: phys chunk pc of row r holds global chunk pc ^ (r&3) ^
// ((r>>2)&3); reader rows ≡ lr mod 16 -> same xor (wm, 16i are multiples of
// 16; row+128 preserves both bit groups). vmcnt ladder ({A:2,B:1} per stage):
// prologue B0,A0,A1 = 5 in flight; steady top vmcnt(2) retires exactly
// {A(kt),B(kt)} keeping A(kt+1); last iteration vmcnt(0).
template <int DO_GELU, int DO_REMAP, int OUT_BF16>
__global__ __launch_bounds__(512) void gemm_kernel(const unsigned short* __restrict__ A,
                                                   const unsigned short* __restrict__ Bt,
                                                   const float* __restrict__ bias,
                                                   const float* __restrict__ res,
                                                   void* __restrict__ outv,
                                                   int M, int N, int K, float scale) {
    __shared__ alignas(16) unsigned short As[3][256 * 32];   // 48 KB
    __shared__ alignas(16) unsigned short Bs[2][128 * 32];   // 16 KB

    // bijective XCD swizzle (m204)
    int nwg = gridDim.x * gridDim.y;
    int lid = blockIdx.y * gridDim.x + blockIdx.x;
    int q8 = nwg >> 3, r8 = nwg & 7;
    int xcd = lid & 7, pos = lid >> 3;
    int nlid = (xcd < r8 ? xcd * (q8 + 1) : r8 * (q8 + 1) + (xcd - r8) * q8) + pos;
    int m0 = (nlid / gridDim.x) * 256;
    int n0 = (nlid % gridDim.x) * 128;

    int t = threadIdx.x;
    int lane = t & 63;
    int wv = t >> 6;                  // 0..7
    int wm = (wv >> 1) * 64;          // 4 m-waves: 0,64,128,192
    int wn = (wv & 1) * 64;           // 2 n-waves: 0,64
    int lr = lane & 15;
    int lq = lane >> 4;

    // staging map: tiles are rows x 32 shorts; 16B slot s = (row = s>>2, pc = s&3);
    // phys chunk pc holds global chunk pc ^ xr(row), xr = (r&3)^((r>>2)&3).
    int rowS = t >> 2;                // 0..127
    int pcS = t & 3;
    int xrS = (rowS & 3) ^ ((rowS >> 2) & 3);
    int gcS = ((pcS ^ xrS) << 3);     // shorts offset within the 32-short row

    // reader swizzle: accessed rows ≡ lr (mod 16) -> same xr as lr
    int xrR = (lr & 3) ^ ((lr >> 2) & 3);
    u32 swB = (u32)((lq ^ xrR) << 4); // byte offset within 64-byte row

    floatx4 acc[4][4];
#pragma unroll
    for (int i = 0; i < 4; i++)
#pragma unroll
        for (int j = 0; j < 4; j++) acc[i][j] = (floatx4)0.f;

    const unsigned short* Abase = A + (size_t)(m0 + rowS) * K + gcS;
    const unsigned short* Bbase = Bt + (size_t)(n0 + rowS) * K + gcS;
    size_t arstep = (size_t)128 * K;  // second A slot: rows 128..255

    auto stageA = [&](int buf, int kk) {
        GLOAD_LDS16(Abase + kk, &As[buf][t * 8]);
        GLOAD_LDS16(Abase + arstep + kk, &As[buf][(512 + t) * 8]);
    };
    auto stageB = [&](int buf, int kk) {
        GLOAD_LDS16(Bbase + kk, &Bs[buf][t * 8]);
    };

    // LDS byte bases for opaque reads
    u32 asBase = LDS_U32(&As[0][0]);
    u32 bsBase = LDS_U32(&Bs[0][0]);
    u32 aRow = (u32)((wm + lr) * 64) + swB;   // row stride 64 B
    u32 bRow = (u32)((wn + lr) * 64) + swB;

    const int nk = K >> 5;            // 12 or 48

    // ---- prologue: B0 [1], A0 [2], A1 [2] (5 loads in flight/thread) ----
    stageB(0, 0);
    stageA(0, 0);
    stageA(1, 32);

    for (int kt = 0; kt < nk; ++kt) {
        int ab = kt % 3;
        int bb = kt & 1;
        // retire A(kt)+B(kt); keep A(kt+1)'s 2 loads in flight
        if (kt + 1 < nk) asm volatile("s_waitcnt vmcnt(2)" ::: "memory");
        else             asm volatile("s_waitcnt vmcnt(0)" ::: "memory");
        __builtin_amdgcn_s_barrier();            // tile kt visible to all waves
        // issue next staging FIRST (2-ahead for A, 1-ahead for B), then compute
        if (kt + 1 < nk) stageB(bb ^ 1, (kt + 1) << 5);
        if (kt + 2 < nk) stageA((kt + 2) % 3, (kt + 2) << 5);

        u32 aB = asBase + (u32)ab * 16384u + aRow;
        u32 bB = bsBase + (u32)bb * 8192u + bRow;

        short8 a0[4], b0[4];
        a0[0] = ds_read128<0>(aB);    a0[1] = ds_read128<1024>(aB);
        a0[2] = ds_read128<2048>(aB); a0[3] = ds_read128<3072>(aB);
        b0[0] = ds_read128<0>(bB);    b0[1] = ds_read128<1024>(bB);
        b0[2] = ds_read128<2048>(bB); b0[3] = ds_read128<3072>(bB);

        asm volatile("s_waitcnt lgkmcnt(0)" ::: "memory");   // all 8 reads done
        __builtin_amdgcn_sched_barrier(0);                   // rule #18 fence
        __builtin_amdgcn_s_setprio(1);
#pragma unroll
        for (int i = 0; i < 4; i++)
#pragma unroll
            for (int j = 0; j < 4; j++)
                acc[i][j] = __builtin_amdgcn_mfma_f32_16x16x32_bf16(a0[i], b0[j], acc[i][j], 0, 0, 0);
        __builtin_amdgcn_s_setprio(0);
        // no trailing barrier: staging targets buffers disjoint from those
        // read this iteration; top barrier bounds wave skew; lgkmcnt(0)
        // inside the iteration guarantees reads complete before next barrier.
    }

#pragma unroll
    for (int j = 0; j < 4; j++) {
        int gcol = n0 + wn + j * 16 + lr;
        float bv = bias[gcol];
#pragma unroll
        for (int i = 0; i < 4; i++) {
#pragma unroll
            for (int r = 0; r < 4; r++) {
                int grow = m0 + wm + i * 16 + lq * 4 + r;
                float val = acc[i][j][r] + bv;
                if (DO_GELU) val = 0.5f * val * (1.f + erff(val * 0.70710678118654752f));
                val *= scale;
                int orow = DO_REMAP ? win2nat(grow) : grow;
                size_t idx = (size_t)orow * N + gcol;
                if (res) val += res[idx];
                if (OUT_BF16) ((unsigned short*)outv)[idx] = f2bf(val);
                else          ((float*)outv)[idx] = val;
            }
        }
    }
}

extern "C" void kernel_launch(void* const* d_in, const int* in_sizes, int n_in,
                              void* d_out, int out_size, void* d_ws, size_t ws_size,
                              hipStream_t stream) {
    const float* x          = (const float*)d_in[0];
    const float* kv         = (const float*)d_in[1];
    const int*   rel_index  = (const int*)d_in[2];
    const float* g1         = (const float*)d_in[5];
    const float* b1         = (const float*)d_in[6];
    const float* Wqkv       = (const float*)d_in[7];
    const float* bqkv       = (const float*)d_in[8];
    const float* bias_table = (const float*)d_in[9];
    const float* Wproj      = (const float*)d_in[10];
    const float* bproj      = (const float*)d_in[11];
    const float* g2         = (const float*)d_in[12];
    const float* b2         = (const float*)d_in[13];
    const float* Wfc1       = (const float*)d_in[14];
    const float* bfc1       = (const float*)d_in[15];
    const float* Wfc2       = (const float*)d_in[16];
    const float* bfc2       = (const float*)d_in[17];
    float* out = (float*)d_out;

    char* ws = (char*)d_ws;
    unsigned short* wq_t   = (unsigned short*)(ws);
    unsigned short* wp_t   = (unsigned short*)(ws + 294912);
    unsigned short* wfc1_t = (unsigned short*)(ws + 589824);
    unsigned short* wfc2_t = (unsigned short*)(ws + 1769472);
    float*          biasx  = (float*)(ws + 2949120);
    unsigned short* bufA   = (unsigned short*)(ws + 3080192);
    unsigned short* bufB   = (unsigned short*)(ws + 3080192 + 38535168);

    const int M = 50176;
    const float scale = 0.17677669529663687f;
    const int full_mlp = (ws_size >= (size_t)3080192 + 38535168 + 154140672);

    // merged preprocessing: 4 transposes + bias expand in ONE dispatch
    prep_kernel<<<(1503372 + 255) / 256, 256, 0, stream>>>(Wqkv, Wproj, Wfc1, Wfc2,
                                                           rel_index, bias_table,
                                                           wq_t, wp_t, wfc1_t, wfc2_t, biasx);

    // LN1 -> windowed (bf16)
    ln_kernel<<<M, 64, 0, stream>>>(x, g1, b1, bufA, 1);
    // q = (hw @ Wq + bq) * scale -> bufB
    gemm_kernel<0, 0, 1><<<dim3(3, M / 256), 512, 0, stream>>>(bufA, wq_t, bqkv, nullptr, bufB,
                                                               M, 384, 384, scale);
    // attention -> bufA
    attn_kernel<<<16 * NHEAD * 4, 256, 0, stream>>>(bufB, kv, biasx, bufA);
    // proj + window_reverse + residual(x) -> d_out (fp32)
    gemm_kernel<0, 1, 0><<<dim3(3, M / 256), 512, 0, stream>>>(bufA, wp_t, bproj, x, d_out,
                                                               M, 384, 384, 1.f);
    // LN2
    ln_kernel<<<M, 64, 0, stream>>>(out, g2, b2, bufA, 0);

    if (full_mlp) {
        gemm_kernel<1, 0, 1><<<dim3(12, M / 256), 512, 0, stream>>>(bufA, wfc1_t, bfc1,
                                                                    nullptr, bufB, M, 1536, 384, 1.f);
        gemm_kernel<0, 0, 0><<<dim3(3, M / 256), 512, 0, stream>>>(bufB, wfc2_t, bfc2,
                                                                   out, out, M, 384, 1536, 1.f);
    } else {
        for (int c = 0; c < 4; c++) {
            size_t ro = (size_t)c * 12544;
            gemm_kernel<1, 0, 1><<<dim3(12, 49), 512, 0, stream>>>(bufA + ro * 384, wfc1_t, bfc1,
                                                                   nullptr, bufB, 12544, 1536, 384, 1.f);
            gemm_kernel<0, 0, 0><<<dim3(3, 49), 512, 0, stream>>>(bufB, wfc2_t, bfc2,
                                                                  out + ro * 384, out + ro * 384,
                                                                  12544, 384, 1536, 1.f);
        }
    }
}

// Round 14
// 568.217 us; speedup vs baseline: 1.3322x; 1.0619x over previous
//
#include <hip/hip_runtime.h>

typedef __attribute__((ext_vector_type(8))) short short8;
typedef __attribute__((ext_vector_type(4))) float floatx4;
typedef unsigned int u32;

#define DIM 384
#define NHEAD 12
#define HDIM 32

__device__ __forceinline__ float bf2f(unsigned int u) {
    union { unsigned int i; float f; } x; x.i = (u & 0xffffu) << 16; return x.f;
}
__device__ __forceinline__ unsigned short f2bf(float f) {
    union { float f; unsigned int i; } x; x.f = f;
    return (unsigned short)((x.i + 0x7fffu + ((x.i >> 16) & 1u)) >> 16);
}

__device__ __forceinline__ int nat2win(int r) {
    int b = r / 3136; int l = r - b * 3136;
    int hh = l / 56, wc = l - hh * 56;
    int wh = hh / 7, nr = hh - wh * 7;
    int ww = wc / 7, nc = wc - ww * 7;
    return ((b << 6) + wh * 8 + ww) * 49 + nr * 7 + nc;
}
__device__ __forceinline__ int win2nat(int r) {
    int w = r / 49; int n = r - w * 49;
    int b = w >> 6; int wi = w & 63;
    int wh = wi >> 3, ww = wi & 7;
    int hh = wh * 7 + n / 7, wc = ww * 7 + n % 7;
    return b * 3136 + hh * 56 + wc;
}

#define GLOAD_LDS16(g, l) \
    __builtin_amdgcn_global_load_lds((const __attribute__((address_space(1))) u32*)(g), \
                                     (__attribute__((address_space(3))) u32*)(l), 16, 0, 0)

#define LDS_U32(p) ((u32)(uintptr_t)(__attribute__((address_space(3))) unsigned short*)(p))

// Opaque LDS read: compiler cannot connect this to global_load_lds writes,
// so it cannot insert its own vmcnt(0) drain — our counted waits are the
// only ordering (m201/m218 pattern; rule #18 fence applied at call sites).
template <int OFF>
__device__ __forceinline__ short8 ds_read128(u32 addr) {
    short8 r;
    asm volatile("ds_read_b128 %0, %1 offset:%2" : "=v"(r) : "v"(addr), "i"(OFF));
    return r;
}

// Merged preprocessing: 4 weight transposes (fp32 -> bf16, N-major) + bias
// expansion, one dispatch instead of five.
__global__ void prep_kernel(const float* __restrict__ Wqkv,
                            const float* __restrict__ Wproj,
                            const float* __restrict__ Wfc1,
                            const float* __restrict__ Wfc2,
                            const int* __restrict__ rel_index,
                            const float* __restrict__ bias_table,
                            unsigned short* __restrict__ wq_t,
                            unsigned short* __restrict__ wp_t,
                            unsigned short* __restrict__ wfc1_t,
                            unsigned short* __restrict__ wfc2_t,
                            float* __restrict__ biasx) {
    int i = blockIdx.x * blockDim.x + threadIdx.x;
    if (i < 147456) {
        int n = i / 384, k = i - n * 384;
        wq_t[i] = f2bf(Wqkv[(size_t)k * 1152 + n]);
        return;
    }
    i -= 147456;
    if (i < 147456) {
        int n = i / 384, k = i - n * 384;
        wp_t[i] = f2bf(Wproj[(size_t)k * 384 + n]);
        return;
    }
    i -= 147456;
    if (i < 589824) {
        int n = i / 384, k = i - n * 384;
        wfc1_t[i] = f2bf(Wfc1[(size_t)k * 1536 + n]);
        return;
    }
    i -= 589824;
    if (i < 589824) {
        int n = i / 1536, k = i - n * 1536;
        wfc2_t[i] = f2bf(Wfc2[(size_t)k * 384 + n]);
        return;
    }
    i -= 589824;
    if (i < 28812) {
        int h = i / 2401, r = i - h * 2401;
        biasx[i] = bias_table[rel_index[r] * NHEAD + h];
    }
}

// LayerNorm over 384, fp32 in -> bf16 out; one wave per row.
__global__ __launch_bounds__(64) void ln_kernel(const float* __restrict__ x,
                                                const float* __restrict__ g,
                                                const float* __restrict__ b,
                                                unsigned short* __restrict__ out,
                                                int windowed) {
    int r = blockIdx.x;
    int lane = threadIdx.x;
    const float* row = x + (size_t)r * DIM;
    float v[6];
    float s = 0.f, ss = 0.f;
#pragma unroll
    for (int j = 0; j < 3; j++) {
        int c = lane + j * 64;
        float2 f = *(const float2*)(row + 2 * c);
        v[2 * j] = f.x; v[2 * j + 1] = f.y;
        s += f.x + f.y; ss += f.x * f.x + f.y * f.y;
    }
#pragma unroll
    for (int m = 1; m < 64; m <<= 1) {
        s += __shfl_xor(s, m);
        ss += __shfl_xor(ss, m);
    }
    float mean = s * (1.f / DIM);
    float var = ss * (1.f / DIM) - mean * mean;
    float rstd = rsqrtf(var + 1e-5f);
    int orow = windowed ? nat2win(r) : r;
    unsigned short* op = out + (size_t)orow * DIM;
#pragma unroll
    for (int j = 0; j < 3; j++) {
        int c = lane + j * 64;
        float2 gg = *(const float2*)(g + 2 * c);
        float2 bb = *(const float2*)(b + 2 * c);
        float o0 = (v[2 * j] - mean) * rstd * gg.x + bb.x;
        float o1 = (v[2 * j + 1] - mean) * rstd * gg.y + bb.y;
        unsigned int w = ((unsigned int)f2bf(o1) << 16) | f2bf(o0);
        *(unsigned int*)(op + 2 * c) = w;
    }
}

// MFMA attention: block = (image b, head h, group of 16 windows).
__global__ __launch_bounds__(256) void attn_kernel(const unsigned short* __restrict__ q,
                                                   const float* __restrict__ kv,
                                                   const float* __restrict__ biasx,
                                                   unsigned short* __restrict__ o) {
    __shared__ alignas(16) unsigned short Ks[64 * 40];   // [token][d] stride 40
    __shared__ alignas(16) unsigned short Vt[32 * 72];   // [d][token] stride 72
    __shared__ float Bi[49 * 52];                        // [qr][k] stride 52
    __shared__ alignas(16) unsigned short Ps[4][16 * 72];// per-wave P tile

    int blk = blockIdx.x;
    int b = blk / 48; int rem = blk - b * 48;
    int h = rem >> 2; int g = rem & 3;
    size_t row_base = (size_t)(b * 64 + g * 16) * 49;

    int t = threadIdx.x;
    int lane = t & 63;
    int wv = t >> 6;
    int lr = lane & 15;
    int lg = lane >> 4;

    const float* kptr = kv + (size_t)(b * NHEAD + h) * 1568;
    for (int idx = t; idx < 392; idx += 256) {
        int row = idx >> 3, seg = idx & 7;
        float4 f = *(const float4*)(kptr + row * 32 + seg * 4);
        ushort4 h4; h4.x = f2bf(f.x); h4.y = f2bf(f.y); h4.z = f2bf(f.z); h4.w = f2bf(f.w);
        *(ushort4*)&Ks[row * 40 + seg * 4] = h4;
    }
    const float* vptr = kv + (size_t)(192 + b * NHEAD + h) * 1568;
    for (int idx = t; idx < 784; idx += 256) {
        int m = idx >> 4, dp = idx & 15;
        float2 f = *(const float2*)(vptr + m * 32 + dp * 2);
        Vt[(2 * dp) * 72 + m]     = f2bf(f.x);
        Vt[(2 * dp + 1) * 72 + m] = f2bf(f.y);
    }
    for (int idx = t; idx < 32 * 23; idx += 256) {      // zero Vt token-pad 49..71
        int d = idx / 23, m = 49 + idx - d * 23;
        Vt[d * 72 + m] = 0;
    }
    const float* bh = biasx + h * 2401;
    for (int idx = t; idx < 2401; idx += 256) {
        int qr = idx / 49, k = idx - qr * 49;
        Bi[qr * 52 + k] = bh[idx];
    }
    __syncthreads();

    short8 bfr[4], vbf[2][2];
#pragma unroll
    for (int ni = 0; ni < 4; ni++)
        bfr[ni] = *(const short8*)&Ks[(ni * 16 + lr) * 40 + lg * 8];
#pragma unroll
    for (int ni = 0; ni < 2; ni++)
#pragma unroll
        for (int ks = 0; ks < 2; ks++)
            vbf[ni][ks] = *(const short8*)&Vt[(ni * 16 + lr) * 72 + ks * 32 + lg * 8];

    const unsigned short* qb = q + row_base * DIM + h * 32 + lg * 8;
    unsigned short* ob = o + row_base * DIM + h * 32;

    short8 af = *(const short8*)(qb + (size_t)(wv * 16 + lr) * DIM);
    for (int tm = wv; tm < 49; tm += 4) {
        short8 af_next;
        if (tm + 4 < 49) af_next = *(const short8*)(qb + (size_t)((tm + 4) * 16 + lr) * DIM);

        floatx4 sfrag[4];
#pragma unroll
        for (int ni = 0; ni < 4; ni++)
            sfrag[ni] = __builtin_amdgcn_mfma_f32_16x16x32_bf16(af, bfr[ni], (floatx4)0.f, 0, 0, 0);

#pragma unroll
        for (int reg = 0; reg < 4; reg++) {
            int r_loc = tm * 16 + lg * 4 + reg;
            int qr = r_loc % 49;
            float mx = -1e30f;
#pragma unroll
            for (int ni = 0; ni < 4; ni++) {
                int k = ni * 16 + lr;
                float s = sfrag[ni][reg];
                if (k < 49) s += Bi[qr * 52 + k];
                else s = -1e30f;
                sfrag[ni][reg] = s;
                mx = fmaxf(mx, s);
            }
#pragma unroll
            for (int j = 1; j < 16; j <<= 1) mx = fmaxf(mx, __shfl_xor(mx, j));
            float sum = 0.f;
#pragma unroll
            for (int ni = 0; ni < 4; ni++) {
                float e = __expf(sfrag[ni][reg] - mx);
                sfrag[ni][reg] = e;
                sum += e;
            }
#pragma unroll
            for (int j = 1; j < 16; j <<= 1) sum += __shfl_xor(sum, j);
            float inv = 1.f / sum;
#pragma unroll
            for (int ni = 0; ni < 4; ni++)
                Ps[wv][(lg * 4 + reg) * 72 + ni * 16 + lr] = f2bf(sfrag[ni][reg] * inv);
        }
        floatx4 ofrag[2] = {(floatx4)0.f, (floatx4)0.f};
#pragma unroll
        for (int ks = 0; ks < 2; ks++) {
            short8 paf = *(const short8*)&Ps[wv][lr * 72 + ks * 32 + lg * 8];
#pragma unroll
            for (int ni = 0; ni < 2; ni++)
                ofrag[ni] = __builtin_amdgcn_mfma_f32_16x16x32_bf16(paf, vbf[ni][ks], ofrag[ni], 0, 0, 0);
        }
#pragma unroll
        for (int reg = 0; reg < 4; reg++) {
            size_t rg = (size_t)(tm * 16 + lg * 4 + reg) * DIM;
#pragma unroll
            for (int ni = 0; ni < 2; ni++)
                ob[rg + ni * 16 + lr] = f2bf(ofrag[ni][reg]);
        }
        af = af_next;
    }
}

// C[M,N] = A[M,K](bf16) @ Bt[N,K](bf16)^T ; 256x128 tile, BK=32, 512 threads.
// R13 K-loop (validated): As[3](48KB, 2 iters ahead) + Bs[2](16KB, 1 ahead)
// = 64 KB -> 2 blocks/CU; one barrier per K-step after counted vmcnt;
// opaque asm ds_read_b128 + lgkmcnt(0) + sched_barrier.
// THIS ROUND: epilogue loop order (i,r,j) with j INNERMOST — a row's four
// 32 B bf16 store segments become back-to-back and merge into full cache
// lines (R13 measured WRITE_SIZE = 2.0x output size with j outermost).
// Bias preloaded into 4 regs; win2nat hoisted to once per row.
template <int DO_GELU, int DO_REMAP, int OUT_BF16>
__global__ __launch_bounds__(512) void gemm_kernel(const unsigned short* __restrict__ A,
                                                   const unsigned short* __restrict__ Bt,
                                                   const float* __restrict__ bias,
                                                   const float* __restrict__ res,
                                                   void* __restrict__ outv,
                                                   int M, int N, int K, float scale) {
    __shared__ alignas(16) unsigned short As[3][256 * 32];   // 48 KB
    __shared__ alignas(16) unsigned short Bs[2][128 * 32];   // 16 KB

    // bijective XCD swizzle (m204)
    int nwg = gridDim.x * gridDim.y;
    int lid = blockIdx.y * gridDim.x + blockIdx.x;
    int q8 = nwg >> 3, r8 = nwg & 7;
    int xcd = lid & 7, pos = lid >> 3;
    int nlid = (xcd < r8 ? xcd * (q8 + 1) : r8 * (q8 + 1) + (xcd - r8) * q8) + pos;
    int m0 = (nlid / gridDim.x) * 256;
    int n0 = (nlid % gridDim.x) * 128;

    int t = threadIdx.x;
    int lane = t & 63;
    int wv = t >> 6;                  // 0..7
    int wm = (wv >> 1) * 64;          // 4 m-waves: 0,64,128,192
    int wn = (wv & 1) * 64;           // 2 n-waves: 0,64
    int lr = lane & 15;
    int lq = lane >> 4;

    // staging map: tiles are rows x 32 shorts; 16B slot s = (row = s>>2, pc = s&3);
    // phys chunk pc holds global chunk pc ^ xr(row), xr = (r&3)^((r>>2)&3).
    int rowS = t >> 2;                // 0..127
    int pcS = t & 3;
    int xrS = (rowS & 3) ^ ((rowS >> 2) & 3);
    int gcS = ((pcS ^ xrS) << 3);     // shorts offset within the 32-short row

    // reader swizzle: accessed rows ≡ lr (mod 16) -> same xr as lr
    int xrR = (lr & 3) ^ ((lr >> 2) & 3);
    u32 swB = (u32)((lq ^ xrR) << 4); // byte offset within 64-byte row

    floatx4 acc[4][4];
#pragma unroll
    for (int i = 0; i < 4; i++)
#pragma unroll
        for (int j = 0; j < 4; j++) acc[i][j] = (floatx4)0.f;

    const unsigned short* Abase = A + (size_t)(m0 + rowS) * K + gcS;
    const unsigned short* Bbase = Bt + (size_t)(n0 + rowS) * K + gcS;
    size_t arstep = (size_t)128 * K;  // second A slot: rows 128..255

    auto stageA = [&](int buf, int kk) {
        GLOAD_LDS16(Abase + kk, &As[buf][t * 8]);
        GLOAD_LDS16(Abase + arstep + kk, &As[buf][(512 + t) * 8]);
    };
    auto stageB = [&](int buf, int kk) {
        GLOAD_LDS16(Bbase + kk, &Bs[buf][t * 8]);
    };

    // LDS byte bases for opaque reads
    u32 asBase = LDS_U32(&As[0][0]);
    u32 bsBase = LDS_U32(&Bs[0][0]);
    u32 aRow = (u32)((wm + lr) * 64) + swB;   // row stride 64 B
    u32 bRow = (u32)((wn + lr) * 64) + swB;

    const int nk = K >> 5;            // 12 or 48

    // ---- prologue: B0 [1], A0 [2], A1 [2] (5 loads in flight/thread) ----
    stageB(0, 0);
    stageA(0, 0);
    stageA(1, 32);

    for (int kt = 0; kt < nk; ++kt) {
        int ab = kt % 3;
        int bb = kt & 1;
        // retire A(kt)+B(kt); keep A(kt+1)'s 2 loads in flight
        if (kt + 1 < nk) asm volatile("s_waitcnt vmcnt(2)" ::: "memory");
        else             asm volatile("s_waitcnt vmcnt(0)" ::: "memory");
        __builtin_amdgcn_s_barrier();            // tile kt visible to all waves
        // issue next staging FIRST (2-ahead for A, 1-ahead for B), then compute
        if (kt + 1 < nk) stageB(bb ^ 1, (kt + 1) << 5);
        if (kt + 2 < nk) stageA((kt + 2) % 3, (kt + 2) << 5);

        u32 aB = asBase + (u32)ab * 16384u + aRow;
        u32 bB = bsBase + (u32)bb * 8192u + bRow;

        short8 a0[4], b0[4];
        a0[0] = ds_read128<0>(aB);    a0[1] = ds_read128<1024>(aB);
        a0[2] = ds_read128<2048>(aB); a0[3] = ds_read128<3072>(aB);
        b0[0] = ds_read128<0>(bB);    b0[1] = ds_read128<1024>(bB);
        b0[2] = ds_read128<2048>(bB); b0[3] = ds_read128<3072>(bB);

        asm volatile("s_waitcnt lgkmcnt(0)" ::: "memory");   // all 8 reads done
        __builtin_amdgcn_sched_barrier(0);                   // rule #18 fence
        __builtin_amdgcn_s_setprio(1);
#pragma unroll
        for (int i = 0; i < 4; i++)
#pragma unroll
            for (int j = 0; j < 4; j++)
                acc[i][j] = __builtin_amdgcn_mfma_f32_16x16x32_bf16(a0[i], b0[j], acc[i][j], 0, 0, 0);
        __builtin_amdgcn_s_setprio(0);
        // no trailing barrier: staging targets buffers disjoint from those
        // read this iteration; top barrier bounds wave skew; lgkmcnt(0)
        // inside the iteration guarantees reads complete before next barrier.
    }

    // ---- epilogue: j INNERMOST so each row's 4x32B segments merge ----
    float bv[4];
#pragma unroll
    for (int j = 0; j < 4; j++) bv[j] = bias[n0 + wn + j * 16 + lr];
#pragma unroll
    for (int i = 0; i < 4; i++) {
#pragma unroll
        for (int r = 0; r < 4; r++) {
            int grow = m0 + wm + i * 16 + lq * 4 + r;
            int orow = DO_REMAP ? win2nat(grow) : grow;
            size_t rowbase = (size_t)orow * N;
#pragma unroll
            for (int j = 0; j < 4; j++) {
                int gcol = n0 + wn + j * 16 + lr;
                float val = acc[i][j][r] + bv[j];
                if (DO_GELU) val = 0.5f * val * (1.f + erff(val * 0.70710678118654752f));
                val *= scale;
                size_t idx = rowbase + gcol;
                if (res) val += res[idx];
                if (OUT_BF16) ((unsigned short*)outv)[idx] = f2bf(val);
                else          ((float*)outv)[idx] = val;
            }
        }
    }
}

extern "C" void kernel_launch(void* const* d_in, const int* in_sizes, int n_in,
                              void* d_out, int out_size, void* d_ws, size_t ws_size,
                              hipStream_t stream) {
    const float* x          = (const float*)d_in[0];
    const float* kv         = (const float*)d_in[1];
    const int*   rel_index  = (const int*)d_in[2];
    const float* g1         = (const float*)d_in[5];
    const float* b1         = (const float*)d_in[6];
    const float* Wqkv       = (const float*)d_in[7];
    const float* bqkv       = (const float*)d_in[8];
    const float* bias_table = (const float*)d_in[9];
    const float* Wproj      = (const float*)d_in[10];
    const float* bproj      = (const float*)d_in[11];
    const float* g2         = (const float*)d_in[12];
    const float* b2         = (const float*)d_in[13];
    const float* Wfc1       = (const float*)d_in[14];
    const float* bfc1       = (const float*)d_in[15];
    const float* Wfc2       = (const float*)d_in[16];
    const float* bfc2       = (const float*)d_in[17];
    float* out = (float*)d_out;

    char* ws = (char*)d_ws;
    unsigned short* wq_t   = (unsigned short*)(ws);
    unsigned short* wp_t   = (unsigned short*)(ws + 294912);
    unsigned short* wfc1_t = (unsigned short*)(ws + 589824);
    unsigned short* wfc2_t = (unsigned short*)(ws + 1769472);
    float*          biasx  = (float*)(ws + 2949120);
    unsigned short* bufA   = (unsigned short*)(ws + 3080192);
    unsigned short* bufB   = (unsigned short*)(ws + 3080192 + 38535168);

    const int M = 50176;
    const float scale = 0.17677669529663687f;
    const int full_mlp = (ws_size >= (size_t)3080192 + 38535168 + 154140672);

    // merged preprocessing: 4 transposes + bias expand in ONE dispatch
    prep_kernel<<<(1503372 + 255) / 256, 256, 0, stream>>>(Wqkv, Wproj, Wfc1, Wfc2,
                                                           rel_index, bias_table,
                                                           wq_t, wp_t, wfc1_t, wfc2_t, biasx);

    // LN1 -> windowed (bf16)
    ln_kernel<<<M, 64, 0, stream>>>(x, g1, b1, bufA, 1);
    // q = (hw @ Wq + bq) * scale -> bufB
    gemm_kernel<0, 0, 1><<<dim3(3, M / 256), 512, 0, stream>>>(bufA, wq_t, bqkv, nullptr, bufB,
                                                               M, 384, 384, scale);
    // attention -> bufA
    attn_kernel<<<16 * NHEAD * 4, 256, 0, stream>>>(bufB, kv, biasx, bufA);
    // proj + window_reverse + residual(x) -> d_out (fp32)
    gemm_kernel<0, 1, 0><<<dim3(3, M / 256), 512, 0, stream>>>(bufA, wp_t, bproj, x, d_out,
                                                               M, 384, 384, 1.f);
    // LN2
    ln_kernel<<<M, 64, 0, stream>>>(out, g2, b2, bufA, 0);

    if (full_mlp) {
        gemm_kernel<1, 0, 1><<<dim3(12, M / 256), 512, 0, stream>>>(bufA, wfc1_t, bfc1,
                                                                    nullptr, bufB, M, 1536, 384, 1.f);
        gemm_kernel<0, 0, 0><<<dim3(3, M / 256), 512, 0, stream>>>(bufB, wfc2_t, bfc2,
                                                                   out, out, M, 384, 1536, 1.f);
    } else {
        for (int c = 0; c < 4; c++) {
            size_t ro = (size_t)c * 12544;
            gemm_kernel<1, 0, 1><<<dim3(12, 49), 512, 0, stream>>>(bufA + ro * 384, wfc1_t, bfc1,
                                                                   nullptr, bufB, 12544, 1536, 384, 1.f);
            gemm_kernel<0, 0, 0><<<dim3(3, 49), 512, 0, stream>>>(bufB, wfc2_t, bfc2,
                                                                  out + ro * 384, out + ro * 384,
                                                                  12544, 384, 1536, 1.f);
        }
    }
}

// Round 15
// 556.591 us; speedup vs baseline: 1.3600x; 1.0209x over previous
//
#include <hip/hip_runtime.h>

typedef __attribute__((ext_vector_type(8))) short short8;
typedef __attribute__((ext_vector_type(4))) float floatx4;
typedef unsigned int u32;

#define DIM 384
#define NHEAD 12
#define HDIM 32

__device__ __forceinline__ float bf2f(unsigned int u) {
    union { unsigned int i; float f; } x; x.i = (u & 0xffffu) << 16; return x.f;
}
__device__ __forceinline__ unsigned short f2bf(float f) {
    union { float f; unsigned int i; } x; x.f = f;
    return (unsigned short)((x.i + 0x7fffu + ((x.i >> 16) & 1u)) >> 16);
}

__device__ __forceinline__ int nat2win(int r) {
    int b = r / 3136; int l = r - b * 3136;
    int hh = l / 56, wc = l - hh * 56;
    int wh = hh / 7, nr = hh - wh * 7;
    int ww = wc / 7, nc = wc - ww * 7;
    return ((b << 6) + wh * 8 + ww) * 49 + nr * 7 + nc;
}
__device__ __forceinline__ int win2nat(int r) {
    int w = r / 49; int n = r - w * 49;
    int b = w >> 6; int wi = w & 63;
    int wh = wi >> 3, ww = wi & 7;
    int hh = wh * 7 + n / 7, wc = ww * 7 + n % 7;
    return b * 3136 + hh * 56 + wc;
}

#define GLOAD_LDS16(g, l) \
    __builtin_amdgcn_global_load_lds((const __attribute__((address_space(1))) u32*)(g), \
                                     (__attribute__((address_space(3))) u32*)(l), 16, 0, 0)

#define LDS_U32(p) ((u32)(uintptr_t)(__attribute__((address_space(3))) unsigned short*)(p))

// Opaque LDS read: compiler cannot connect this to global_load_lds writes,
// so it cannot insert its own vmcnt(0) drain — our counted waits are the
// only ordering (m201/m218 pattern; rule #18 fence applied at call sites).
template <int OFF>
__device__ __forceinline__ short8 ds_read128(u32 addr) {
    short8 r;
    asm volatile("ds_read_b128 %0, %1 offset:%2" : "=v"(r) : "v"(addr), "i"(OFF));
    return r;
}

// Merged preprocessing: 4 weight transposes (fp32 -> bf16, N-major) + bias
// expansion, one dispatch instead of five.
__global__ void prep_kernel(const float* __restrict__ Wqkv,
                            const float* __restrict__ Wproj,
                            const float* __restrict__ Wfc1,
                            const float* __restrict__ Wfc2,
                            const int* __restrict__ rel_index,
                            const float* __restrict__ bias_table,
                            unsigned short* __restrict__ wq_t,
                            unsigned short* __restrict__ wp_t,
                            unsigned short* __restrict__ wfc1_t,
                            unsigned short* __restrict__ wfc2_t,
                            float* __restrict__ biasx) {
    int i = blockIdx.x * blockDim.x + threadIdx.x;
    if (i < 147456) {
        int n = i / 384, k = i - n * 384;
        wq_t[i] = f2bf(Wqkv[(size_t)k * 1152 + n]);
        return;
    }
    i -= 147456;
    if (i < 147456) {
        int n = i / 384, k = i - n * 384;
        wp_t[i] = f2bf(Wproj[(size_t)k * 384 + n]);
        return;
    }
    i -= 147456;
    if (i < 589824) {
        int n = i / 384, k = i - n * 384;
        wfc1_t[i] = f2bf(Wfc1[(size_t)k * 1536 + n]);
        return;
    }
    i -= 589824;
    if (i < 589824) {
        int n = i / 1536, k = i - n * 1536;
        wfc2_t[i] = f2bf(Wfc2[(size_t)k * 384 + n]);
        return;
    }
    i -= 589824;
    if (i < 28812) {
        int h = i / 2401, r = i - h * 2401;
        biasx[i] = bias_table[rel_index[r] * NHEAD + h];
    }
}

// LayerNorm over 384, fp32 in -> bf16 out.
// 4 rows per 256-thread block (one wave per row, rows independent) —
// cuts block count 50176 -> 12544 (dispatch overhead was the dominant cost
// for this ~115 MB memory-bound op).
__global__ __launch_bounds__(256) void ln_kernel(const float* __restrict__ x,
                                                 const float* __restrict__ g,
                                                 const float* __restrict__ b,
                                                 unsigned short* __restrict__ out,
                                                 int windowed) {
    int r = blockIdx.x * 4 + (threadIdx.x >> 6);
    int lane = threadIdx.x & 63;
    const float* row = x + (size_t)r * DIM;
    float v[6];
    float s = 0.f, ss = 0.f;
#pragma unroll
    for (int j = 0; j < 3; j++) {
        int c = lane + j * 64;
        float2 f = *(const float2*)(row + 2 * c);
        v[2 * j] = f.x; v[2 * j + 1] = f.y;
        s += f.x + f.y; ss += f.x * f.x + f.y * f.y;
    }
#pragma unroll
    for (int m = 1; m < 64; m <<= 1) {
        s += __shfl_xor(s, m);
        ss += __shfl_xor(ss, m);
    }
    float mean = s * (1.f / DIM);
    float var = ss * (1.f / DIM) - mean * mean;
    float rstd = rsqrtf(var + 1e-5f);
    int orow = windowed ? nat2win(r) : r;
    unsigned short* op = out + (size_t)orow * DIM;
#pragma unroll
    for (int j = 0; j < 3; j++) {
        int c = lane + j * 64;
        float2 gg = *(const float2*)(g + 2 * c);
        float2 bb = *(const float2*)(b + 2 * c);
        float o0 = (v[2 * j] - mean) * rstd * gg.x + bb.x;
        float o1 = (v[2 * j + 1] - mean) * rstd * gg.y + bb.y;
        unsigned int w = ((unsigned int)f2bf(o1) << 16) | f2bf(o0);
        *(unsigned int*)(op + 2 * c) = w;
    }
}

// MFMA attention: block = (image b, head h, group of 16 windows).
__global__ __launch_bounds__(256) void attn_kernel(const unsigned short* __restrict__ q,
                                                   const float* __restrict__ kv,
                                                   const float* __restrict__ biasx,
                                                   unsigned short* __restrict__ o) {
    __shared__ alignas(16) unsigned short Ks[64 * 40];   // [token][d] stride 40
    __shared__ alignas(16) unsigned short Vt[32 * 72];   // [d][token] stride 72
    __shared__ float Bi[49 * 52];                        // [qr][k] stride 52
    __shared__ alignas(16) unsigned short Ps[4][16 * 72];// per-wave P tile

    int blk = blockIdx.x;
    int b = blk / 48; int rem = blk - b * 48;
    int h = rem >> 2; int g = rem & 3;
    size_t row_base = (size_t)(b * 64 + g * 16) * 49;

    int t = threadIdx.x;
    int lane = t & 63;
    int wv = t >> 6;
    int lr = lane & 15;
    int lg = lane >> 4;

    const float* kptr = kv + (size_t)(b * NHEAD + h) * 1568;
    for (int idx = t; idx < 392; idx += 256) {
        int row = idx >> 3, seg = idx & 7;
        float4 f = *(const float4*)(kptr + row * 32 + seg * 4);
        ushort4 h4; h4.x = f2bf(f.x); h4.y = f2bf(f.y); h4.z = f2bf(f.z); h4.w = f2bf(f.w);
        *(ushort4*)&Ks[row * 40 + seg * 4] = h4;
    }
    const float* vptr = kv + (size_t)(192 + b * NHEAD + h) * 1568;
    for (int idx = t; idx < 784; idx += 256) {
        int m = idx >> 4, dp = idx & 15;
        float2 f = *(const float2*)(vptr + m * 32 + dp * 2);
        Vt[(2 * dp) * 72 + m]     = f2bf(f.x);
        Vt[(2 * dp + 1) * 72 + m] = f2bf(f.y);
    }
    for (int idx = t; idx < 32 * 23; idx += 256) {      // zero Vt token-pad 49..71
        int d = idx / 23, m = 49 + idx - d * 23;
        Vt[d * 72 + m] = 0;
    }
    const float* bh = biasx + h * 2401;
    for (int idx = t; idx < 2401; idx += 256) {
        int qr = idx / 49, k = idx - qr * 49;
        Bi[qr * 52 + k] = bh[idx];
    }
    __syncthreads();

    short8 bfr[4], vbf[2][2];
#pragma unroll
    for (int ni = 0; ni < 4; ni++)
        bfr[ni] = *(const short8*)&Ks[(ni * 16 + lr) * 40 + lg * 8];
#pragma unroll
    for (int ni = 0; ni < 2; ni++)
#pragma unroll
        for (int ks = 0; ks < 2; ks++)
            vbf[ni][ks] = *(const short8*)&Vt[(ni * 16 + lr) * 72 + ks * 32 + lg * 8];

    const unsigned short* qb = q + row_base * DIM + h * 32 + lg * 8;
    unsigned short* ob = o + row_base * DIM + h * 32;

    short8 af = *(const short8*)(qb + (size_t)(wv * 16 + lr) * DIM);
    for (int tm = wv; tm < 49; tm += 4) {
        short8 af_next;
        if (tm + 4 < 49) af_next = *(const short8*)(qb + (size_t)((tm + 4) * 16 + lr) * DIM);

        floatx4 sfrag[4];
#pragma unroll
        for (int ni = 0; ni < 4; ni++)
            sfrag[ni] = __builtin_amdgcn_mfma_f32_16x16x32_bf16(af, bfr[ni], (floatx4)0.f, 0, 0, 0);

#pragma unroll
        for (int reg = 0; reg < 4; reg++) {
            int r_loc = tm * 16 + lg * 4 + reg;
            int qr = r_loc % 49;
            float mx = -1e30f;
#pragma unroll
            for (int ni = 0; ni < 4; ni++) {
                int k = ni * 16 + lr;
                float s = sfrag[ni][reg];
                if (k < 49) s += Bi[qr * 52 + k];
                else s = -1e30f;
                sfrag[ni][reg] = s;
                mx = fmaxf(mx, s);
            }
#pragma unroll
            for (int j = 1; j < 16; j <<= 1) mx = fmaxf(mx, __shfl_xor(mx, j));
            float sum = 0.f;
#pragma unroll
            for (int ni = 0; ni < 4; ni++) {
                float e = __expf(sfrag[ni][reg] - mx);
                sfrag[ni][reg] = e;
                sum += e;
            }
#pragma unroll
            for (int j = 1; j < 16; j <<= 1) sum += __shfl_xor(sum, j);
            float inv = 1.f / sum;
#pragma unroll
            for (int ni = 0; ni < 4; ni++)
                Ps[wv][(lg * 4 + reg) * 72 + ni * 16 + lr] = f2bf(sfrag[ni][reg] * inv);
        }
        floatx4 ofrag[2] = {(floatx4)0.f, (floatx4)0.f};
#pragma unroll
        for (int ks = 0; ks < 2; ks++) {
            short8 paf = *(const short8*)&Ps[wv][lr * 72 + ks * 32 + lg * 8];
#pragma unroll
            for (int ni = 0; ni < 2; ni++)
                ofrag[ni] = __builtin_amdgcn_mfma_f32_16x16x32_bf16(paf, vbf[ni][ks], ofrag[ni], 0, 0, 0);
        }
#pragma unroll
        for (int reg = 0; reg < 4; reg++) {
            size_t rg = (size_t)(tm * 16 + lg * 4 + reg) * DIM;
#pragma unroll
            for (int ni = 0; ni < 2; ni++)
                ob[rg + ni * 16 + lr] = f2bf(ofrag[ni][reg]);
        }
        af = af_next;
    }
}

// C[M,N] = A[M,K](bf16) @ Bt[N,K](bf16)^T ; 256x128 tile, BK=32, 512 threads.
// R14 (best measured): As[3](48KB, 2 iters ahead) + Bs[2](16KB, 1 ahead)
// = 64 KB -> 2 blocks/CU; one barrier per K-step after counted vmcnt;
// opaque asm ds_read_b128 + lgkmcnt(0) + sched_barrier; epilogue with j
// innermost (full-line write merging — R14 halved WRITE_SIZE).
template <int DO_GELU, int DO_REMAP, int OUT_BF16>
__global__ __launch_bounds__(512) void gemm_kernel(const unsigned short* __restrict__ A,
                                                   const unsigned short* __restrict__ Bt,
                                                   const float* __restrict__ bias,
                                                   const float* __restrict__ res,
                                                   void* __restrict__ outv,
                                                   int M, int N, int K, float scale) {
    __shared__ alignas(16) unsigned short As[3][256 * 32];   // 48 KB
    __shared__ alignas(16) unsigned short Bs[2][128 * 32];   // 16 KB

    // bijective XCD swizzle (m204)
    int nwg = gridDim.x * gridDim.y;
    int lid = blockIdx.y * gridDim.x + blockIdx.x;
    int q8 = nwg >> 3, r8 = nwg & 7;
    int xcd = lid & 7, pos = lid >> 3;
    int nlid = (xcd < r8 ? xcd * (q8 + 1) : r8 * (q8 + 1) + (xcd - r8) * q8) + pos;
    int m0 = (nlid / gridDim.x) * 256;
    int n0 = (nlid % gridDim.x) * 128;

    int t = threadIdx.x;
    int lane = t & 63;
    int wv = t >> 6;                  // 0..7
    int wm = (wv >> 1) * 64;          // 4 m-waves: 0,64,128,192
    int wn = (wv & 1) * 64;           // 2 n-waves: 0,64
    int lr = lane & 15;
    int lq = lane >> 4;

    // staging map: tiles are rows x 32 shorts; 16B slot s = (row = s>>2, pc = s&3);
    // phys chunk pc holds global chunk pc ^ xr(row), xr = (r&3)^((r>>2)&3).
    int rowS = t >> 2;                // 0..127
    int pcS = t & 3;
    int xrS = (rowS & 3) ^ ((rowS >> 2) & 3);
    int gcS = ((pcS ^ xrS) << 3);     // shorts offset within the 32-short row

    // reader swizzle: accessed rows ≡ lr (mod 16) -> same xr as lr
    int xrR = (lr & 3) ^ ((lr >> 2) & 3);
    u32 swB = (u32)((lq ^ xrR) << 4); // byte offset within 64-byte row

    floatx4 acc[4][4];
#pragma unroll
    for (int i = 0; i < 4; i++)
#pragma unroll
        for (int j = 0; j < 4; j++) acc[i][j] = (floatx4)0.f;

    const unsigned short* Abase = A + (size_t)(m0 + rowS) * K + gcS;
    const unsigned short* Bbase = Bt + (size_t)(n0 + rowS) * K + gcS;
    size_t arstep = (size_t)128 * K;  // second A slot: rows 128..255

    auto stageA = [&](int buf, int kk) {
        GLOAD_LDS16(Abase + kk, &As[buf][t * 8]);
        GLOAD_LDS16(Abase + arstep + kk, &As[buf][(512 + t) * 8]);
    };
    auto stageB = [&](int buf, int kk) {
        GLOAD_LDS16(Bbase + kk, &Bs[buf][t * 8]);
    };

    // LDS byte bases for opaque reads
    u32 asBase = LDS_U32(&As[0][0]);
    u32 bsBase = LDS_U32(&Bs[0][0]);
    u32 aRow = (u32)((wm + lr) * 64) + swB;   // row stride 64 B
    u32 bRow = (u32)((wn + lr) * 64) + swB;

    const int nk = K >> 5;            // 12 or 48

    // ---- prologue: B0 [1], A0 [2], A1 [2] (5 loads in flight/thread) ----
    stageB(0, 0);
    stageA(0, 0);
    stageA(1, 32);

    for (int kt = 0; kt < nk; ++kt) {
        int ab = kt % 3;
        int bb = kt & 1;
        // retire A(kt)+B(kt); keep A(kt+1)'s 2 loads in flight
        if (kt + 1 < nk) asm volatile("s_waitcnt vmcnt(2)" ::: "memory");
        else             asm volatile("s_waitcnt vmcnt(0)" ::: "memory");
        __builtin_amdgcn_s_barrier();            // tile kt visible to all waves
        // issue next staging FIRST (2-ahead for A, 1-ahead for B), then compute
        if (kt + 1 < nk) stageB(bb ^ 1, (kt + 1) << 5);
        if (kt + 2 < nk) stageA((kt + 2) % 3, (kt + 2) << 5);

        u32 aB = asBase + (u32)ab * 16384u + aRow;
        u32 bB = bsBase + (u32)bb * 8192u + bRow;

        short8 a0[4], b0[4];
        a0[0] = ds_read128<0>(aB);    a0[1] = ds_read128<1024>(aB);
        a0[2] = ds_read128<2048>(aB); a0[3] = ds_read128<3072>(aB);
        b0[0] = ds_read128<0>(bB);    b0[1] = ds_read128<1024>(bB);
        b0[2] = ds_read128<2048>(bB); b0[3] = ds_read128<3072>(bB);

        asm volatile("s_waitcnt lgkmcnt(0)" ::: "memory");   // all 8 reads done
        __builtin_amdgcn_sched_barrier(0);                   // rule #18 fence
        __builtin_amdgcn_s_setprio(1);
#pragma unroll
        for (int i = 0; i < 4; i++)
#pragma unroll
            for (int j = 0; j < 4; j++)
                acc[i][j] = __builtin_amdgcn_mfma_f32_16x16x32_bf16(a0[i], b0[j], acc[i][j], 0, 0, 0);
        __builtin_amdgcn_s_setprio(0);
        // no trailing barrier: staging targets buffers disjoint from those
        // read this iteration; top barrier bounds wave skew; lgkmcnt(0)
        // inside the iteration guarantees reads complete before next barrier.
    }

    // ---- epilogue: j INNERMOST so each row's 4x32B segments merge ----
    float bv[4];
#pragma unroll
    for (int j = 0; j < 4; j++) bv[j] = bias[n0 + wn + j * 16 + lr];
#pragma unroll
    for (int i = 0; i < 4; i++) {
#pragma unroll
        for (int r = 0; r < 4; r++) {
            int grow = m0 + wm + i * 16 + lq * 4 + r;
            int orow = DO_REMAP ? win2nat(grow) : grow;
            size_t rowbase = (size_t)orow * N;
#pragma unroll
            for (int j = 0; j < 4; j++) {
                int gcol = n0 + wn + j * 16 + lr;
                float val = acc[i][j][r] + bv[j];
                if (DO_GELU) val = 0.5f * val * (1.f + erff(val * 0.70710678118654752f));
                val *= scale;
                size_t idx = rowbase + gcol;
                if (res) val += res[idx];
                if (OUT_BF16) ((unsigned short*)outv)[idx] = f2bf(val);
                else          ((float*)outv)[idx] = val;
            }
        }
    }
}

extern "C" void kernel_launch(void* const* d_in, const int* in_sizes, int n_in,
                              void* d_out, int out_size, void* d_ws, size_t ws_size,
                              hipStream_t stream) {
    const float* x          = (const float*)d_in[0];
    const float* kv         = (const float*)d_in[1];
    const int*   rel_index  = (const int*)d_in[2];
    const float* g1         = (const float*)d_in[5];
    const float* b1         = (const float*)d_in[6];
    const float* Wqkv       = (const float*)d_in[7];
    const float* bqkv       = (const float*)d_in[8];
    const float* bias_table = (const float*)d_in[9];
    const float* Wproj      = (const float*)d_in[10];
    const float* bproj      = (const float*)d_in[11];
    const float* g2         = (const float*)d_in[12];
    const float* b2         = (const float*)d_in[13];
    const float* Wfc1       = (const float*)d_in[14];
    const float* bfc1       = (const float*)d_in[15];
    const float* Wfc2       = (const float*)d_in[16];
    const float* bfc2       = (const float*)d_in[17];
    float* out = (float*)d_out;

    char* ws = (char*)d_ws;
    unsigned short* wq_t   = (unsigned short*)(ws);
    unsigned short* wp_t   = (unsigned short*)(ws + 294912);
    unsigned short* wfc1_t = (unsigned short*)(ws + 589824);
    unsigned short* wfc2_t = (unsigned short*)(ws + 1769472);
    float*          biasx  = (float*)(ws + 2949120);
    unsigned short* bufA   = (unsigned short*)(ws + 3080192);
    unsigned short* bufB   = (unsigned short*)(ws + 3080192 + 38535168);

    const int M = 50176;
    const float scale = 0.17677669529663687f;
    const int full_mlp = (ws_size >= (size_t)3080192 + 38535168 + 154140672);

    // merged preprocessing: 4 transposes + bias expand in ONE dispatch
    prep_kernel<<<(1503372 + 255) / 256, 256, 0, stream>>>(Wqkv, Wproj, Wfc1, Wfc2,
                                                           rel_index, bias_table,
                                                           wq_t, wp_t, wfc1_t, wfc2_t, biasx);

    // LN1 -> windowed (bf16); 4 rows per block
    ln_kernel<<<M / 4, 256, 0, stream>>>(x, g1, b1, bufA, 1);
    // q = (hw @ Wq + bq) * scale -> bufB
    gemm_kernel<0, 0, 1><<<dim3(3, M / 256), 512, 0, stream>>>(bufA, wq_t, bqkv, nullptr, bufB,
                                                               M, 384, 384, scale);
    // attention -> bufA
    attn_kernel<<<16 * NHEAD * 4, 256, 0, stream>>>(bufB, kv, biasx, bufA);
    // proj + window_reverse + residual(x) -> d_out (fp32)
    gemm_kernel<0, 1, 0><<<dim3(3, M / 256), 512, 0, stream>>>(bufA, wp_t, bproj, x, d_out,
                                                               M, 384, 384, 1.f);
    // LN2; 4 rows per block
    ln_kernel<<<M / 4, 256, 0, stream>>>(out, g2, b2, bufA, 0);

    if (full_mlp) {
        gemm_kernel<1, 0, 1><<<dim3(12, M / 256), 512, 0, stream>>>(bufA, wfc1_t, bfc1,
                                                                    nullptr, bufB, M, 1536, 384, 1.f);
        gemm_kernel<0, 0, 0><<<dim3(3, M / 256), 512, 0, stream>>>(bufB, wfc2_t, bfc2,
                                                                   out, out, M, 384, 1536, 1.f);
    } else {
        for (int c = 0; c < 4; c++) {
            size_t ro = (size_t)c * 12544;
            gemm_kernel<1, 0, 1><<<dim3(12, 49), 512, 0, stream>>>(bufA + ro * 384, wfc1_t, bfc1,
                                                                   nullptr, bufB, 12544, 1536, 384, 1.f);
            gemm_kernel<0, 0, 0><<<dim3(3, 49), 512, 0, stream>>>(bufB, wfc2_t, bfc2,
                                                                  out + ro * 384, out + ro * 384,
                                                                  12544, 384, 1536, 1.f);
        }
    }
}

// Round 16
// 549.585 us; speedup vs baseline: 1.3773x; 1.0127x over previous
//
#include <hip/hip_runtime.h>

typedef __attribute__((ext_vector_type(8))) short short8;
typedef __attribute__((ext_vector_type(4))) float floatx4;
typedef unsigned int u32;

#define DIM 384
#define NHEAD 12
#define HDIM 32

__device__ __forceinline__ float bf2f(unsigned int u) {
    union { unsigned int i; float f; } x; x.i = (u & 0xffffu) << 16; return x.f;
}
__device__ __forceinline__ unsigned short f2bf(float f) {
    union { float f; unsigned int i; } x; x.f = f;
    return (unsigned short)((x.i + 0x7fffu + ((x.i >> 16) & 1u)) >> 16);
}

__device__ __forceinline__ int nat2win(int r) {
    int b = r / 3136; int l = r - b * 3136;
    int hh = l / 56, wc = l - hh * 56;
    int wh = hh / 7, nr = hh - wh * 7;
    int ww = wc / 7, nc = wc - ww * 7;
    return ((b << 6) + wh * 8 + ww) * 49 + nr * 7 + nc;
}
__device__ __forceinline__ int win2nat(int r) {
    int w = r / 49; int n = r - w * 49;
    int b = w >> 6; int wi = w & 63;
    int wh = wi >> 3, ww = wi & 7;
    int hh = wh * 7 + n / 7, wc = ww * 7 + n % 7;
    return b * 3136 + hh * 56 + wc;
}

#define GLOAD_LDS16(g, l) \
    __builtin_amdgcn_global_load_lds((const __attribute__((address_space(1))) u32*)(g), \
                                     (__attribute__((address_space(3))) u32*)(l), 16, 0, 0)

#define LDS_U32(p) ((u32)(uintptr_t)(__attribute__((address_space(3))) unsigned short*)(p))

// Opaque LDS read: compiler cannot connect this to global_load_lds writes,
// so it cannot insert its own vmcnt(0) drain — our counted waits are the
// only ordering (m201/m218 pattern; rule #18 fence applied at call sites).
template <int OFF>
__device__ __forceinline__ short8 ds_read128(u32 addr) {
    short8 r;
    asm volatile("ds_read_b128 %0, %1 offset:%2" : "=v"(r) : "v"(addr), "i"(OFF));
    return r;
}

// Merged preprocessing v2: coalesced LDS-tile transposes (fp32 -> bf16,
// N-major) + bias expansion. Previous version read at stride ld*4B (one
// 64B line per lane). 32x32 tiles, [32][33] padding; reads coalesced on n,
// writes coalesced on k. Segments (32x32 tiles):
//   [0,144)    wq  (K=384,N=384,ld=1152)    [144,288)  wp  (384,384,384)
//   [288,864)  wfc1(K=384,N=1536,ld=1536)   [864,1440) wfc2(K=1536,N=384,ld=384)
//   [1440,1553) bias expand (28812 elements)
__global__ __launch_bounds__(256) void prep_kernel(const float* __restrict__ Wqkv,
                                                   const float* __restrict__ Wproj,
                                                   const float* __restrict__ Wfc1,
                                                   const float* __restrict__ Wfc2,
                                                   const int* __restrict__ rel_index,
                                                   const float* __restrict__ bias_table,
                                                   unsigned short* __restrict__ wq_t,
                                                   unsigned short* __restrict__ wp_t,
                                                   unsigned short* __restrict__ wfc1_t,
                                                   unsigned short* __restrict__ wfc2_t,
                                                   float* __restrict__ biasx) {
    int blk = blockIdx.x;
    if (blk < 1440) {
        __shared__ float tile[32][33];
        const float* src; unsigned short* dst; int ld, K, tilesN, rel;
        if (blk < 144)      { src = Wqkv;  dst = wq_t;   ld = 1152; K = 384;  tilesN = 12; rel = blk; }
        else if (blk < 288) { src = Wproj; dst = wp_t;   ld = 384;  K = 384;  tilesN = 12; rel = blk - 144; }
        else if (blk < 864) { src = Wfc1;  dst = wfc1_t; ld = 1536; K = 384;  tilesN = 48; rel = blk - 288; }
        else                { src = Wfc2;  dst = wfc2_t; ld = 384;  K = 1536; tilesN = 12; rel = blk - 864; }
        int tk = rel / tilesN, tn = rel - tk * tilesN;
        int k0 = tk * 32, n0 = tn * 32;
        int c = threadIdx.x & 31, rr = threadIdx.x >> 5;   // 8 rows per pass
#pragma unroll
        for (int p = 0; p < 4; p++) {
            int kk = rr + p * 8;
            tile[kk][c] = src[(size_t)(k0 + kk) * ld + n0 + c];   // coalesced on n
        }
        __syncthreads();
#pragma unroll
        for (int p = 0; p < 4; p++) {
            int nn = rr + p * 8;
            dst[(size_t)(n0 + nn) * K + k0 + c] = f2bf(tile[c][nn]);  // coalesced on k
        }
    } else {
        int i = (blk - 1440) * 256 + threadIdx.x;
        if (i < 28812) {
            int h = i / 2401, r = i - h * 2401;
            biasx[i] = bias_table[rel_index[r] * NHEAD + h];
        }
    }
}

// LayerNorm over 384, fp32 in -> bf16 out.
// 8 rows per 512-thread block (one wave per row, rows independent).
__global__ __launch_bounds__(512) void ln_kernel(const float* __restrict__ x,
                                                 const float* __restrict__ g,
                                                 const float* __restrict__ b,
                                                 unsigned short* __restrict__ out,
                                                 int windowed) {
    int r = blockIdx.x * 8 + (threadIdx.x >> 6);
    int lane = threadIdx.x & 63;
    const float* row = x + (size_t)r * DIM;
    float v[6];
    float s = 0.f, ss = 0.f;
#pragma unroll
    for (int j = 0; j < 3; j++) {
        int c = lane + j * 64;
        float2 f = *(const float2*)(row + 2 * c);
        v[2 * j] = f.x; v[2 * j + 1] = f.y;
        s += f.x + f.y; ss += f.x * f.x + f.y * f.y;
    }
#pragma unroll
    for (int m = 1; m < 64; m <<= 1) {
        s += __shfl_xor(s, m);
        ss += __shfl_xor(ss, m);
    }
    float mean = s * (1.f / DIM);
    float var = ss * (1.f / DIM) - mean * mean;
    float rstd = rsqrtf(var + 1e-5f);
    int orow = windowed ? nat2win(r) : r;
    unsigned short* op = out + (size_t)orow * DIM;
#pragma unroll
    for (int j = 0; j < 3; j++) {
        int c = lane + j * 64;
        float2 gg = *(const float2*)(g + 2 * c);
        float2 bb = *(const float2*)(b + 2 * c);
        float o0 = (v[2 * j] - mean) * rstd * gg.x + bb.x;
        float o1 = (v[2 * j + 1] - mean) * rstd * gg.y + bb.y;
        unsigned int w = ((unsigned int)f2bf(o1) << 16) | f2bf(o0);
        *(unsigned int*)(op + 2 * c) = w;
    }
}

// MFMA attention: block = (image b, head h, group of 16 windows).
__global__ __launch_bounds__(256) void attn_kernel(const unsigned short* __restrict__ q,
                                                   const float* __restrict__ kv,
                                                   const float* __restrict__ biasx,
                                                   unsigned short* __restrict__ o) {
    __shared__ alignas(16) unsigned short Ks[64 * 40];   // [token][d] stride 40
    __shared__ alignas(16) unsigned short Vt[32 * 72];   // [d][token] stride 72
    __shared__ float Bi[49 * 52];                        // [qr][k] stride 52
    __shared__ alignas(16) unsigned short Ps[4][16 * 72];// per-wave P tile

    int blk = blockIdx.x;
    int b = blk / 48; int rem = blk - b * 48;
    int h = rem >> 2; int g = rem & 3;
    size_t row_base = (size_t)(b * 64 + g * 16) * 49;

    int t = threadIdx.x;
    int lane = t & 63;
    int wv = t >> 6;
    int lr = lane & 15;
    int lg = lane >> 4;

    const float* kptr = kv + (size_t)(b * NHEAD + h) * 1568;
    for (int idx = t; idx < 392; idx += 256) {
        int row = idx >> 3, seg = idx & 7;
        float4 f = *(const float4*)(kptr + row * 32 + seg * 4);
        ushort4 h4; h4.x = f2bf(f.x); h4.y = f2bf(f.y); h4.z = f2bf(f.z); h4.w = f2bf(f.w);
        *(ushort4*)&Ks[row * 40 + seg * 4] = h4;
    }
    const float* vptr = kv + (size_t)(192 + b * NHEAD + h) * 1568;
    for (int idx = t; idx < 784; idx += 256) {
        int m = idx >> 4, dp = idx & 15;
        float2 f = *(const float2*)(vptr + m * 32 + dp * 2);
        Vt[(2 * dp) * 72 + m]     = f2bf(f.x);
        Vt[(2 * dp + 1) * 72 + m] = f2bf(f.y);
    }
    for (int idx = t; idx < 32 * 23; idx += 256) {      // zero Vt token-pad 49..71
        int d = idx / 23, m = 49 + idx - d * 23;
        Vt[d * 72 + m] = 0;
    }
    const float* bh = biasx + h * 2401;
    for (int idx = t; idx < 2401; idx += 256) {
        int qr = idx / 49, k = idx - qr * 49;
        Bi[qr * 52 + k] = bh[idx];
    }
    __syncthreads();

    short8 bfr[4], vbf[2][2];
#pragma unroll
    for (int ni = 0; ni < 4; ni++)
        bfr[ni] = *(const short8*)&Ks[(ni * 16 + lr) * 40 + lg * 8];
#pragma unroll
    for (int ni = 0; ni < 2; ni++)
#pragma unroll
        for (int ks = 0; ks < 2; ks++)
            vbf[ni][ks] = *(const short8*)&Vt[(ni * 16 + lr) * 72 + ks * 32 + lg * 8];

    const unsigned short* qb = q + row_base * DIM + h * 32 + lg * 8;
    unsigned short* ob = o + row_base * DIM + h * 32;

    short8 af = *(const short8*)(qb + (size_t)(wv * 16 + lr) * DIM);
    for (int tm = wv; tm < 49; tm += 4) {
        short8 af_next;
        if (tm + 4 < 49) af_next = *(const short8*)(qb + (size_t)((tm + 4) * 16 + lr) * DIM);

        floatx4 sfrag[4];
#pragma unroll
        for (int ni = 0; ni < 4; ni++)
            sfrag[ni] = __builtin_amdgcn_mfma_f32_16x16x32_bf16(af, bfr[ni], (floatx4)0.f, 0, 0, 0);

#pragma unroll
        for (int reg = 0; reg < 4; reg++) {
            int r_loc = tm * 16 + lg * 4 + reg;
            int qr = r_loc % 49;
            float mx = -1e30f;
#pragma unroll
            for (int ni = 0; ni < 4; ni++) {
                int k = ni * 16 + lr;
                float s = sfrag[ni][reg];
                if (k < 49) s += Bi[qr * 52 + k];
                else s = -1e30f;
                sfrag[ni][reg] = s;
                mx = fmaxf(mx, s);
            }
#pragma unroll
            for (int j = 1; j < 16; j <<= 1) mx = fmaxf(mx, __shfl_xor(mx, j));
            float sum = 0.f;
#pragma unroll
            for (int ni = 0; ni < 4; ni++) {
                float e = __expf(sfrag[ni][reg] - mx);
                sfrag[ni][reg] = e;
                sum += e;
            }
#pragma unroll
            for (int j = 1; j < 16; j <<= 1) sum += __shfl_xor(sum, j);
            float inv = 1.f / sum;
#pragma unroll
            for (int ni = 0; ni < 4; ni++)
                Ps[wv][(lg * 4 + reg) * 72 + ni * 16 + lr] = f2bf(sfrag[ni][reg] * inv);
        }
        floatx4 ofrag[2] = {(floatx4)0.f, (floatx4)0.f};
#pragma unroll
        for (int ks = 0; ks < 2; ks++) {
            short8 paf = *(const short8*)&Ps[wv][lr * 72 + ks * 32 + lg * 8];
#pragma unroll
            for (int ni = 0; ni < 2; ni++)
                ofrag[ni] = __builtin_amdgcn_mfma_f32_16x16x32_bf16(paf, vbf[ni][ks], ofrag[ni], 0, 0, 0);
        }
#pragma unroll
        for (int reg = 0; reg < 4; reg++) {
            size_t rg = (size_t)(tm * 16 + lg * 4 + reg) * DIM;
#pragma unroll
            for (int ni = 0; ni < 2; ni++)
                ob[rg + ni * 16 + lr] = f2bf(ofrag[ni][reg]);
        }
        af = af_next;
    }
}

// C[M,N] = A[M,K](bf16) @ Bt[N,K](bf16)^T ; 256x128 tile, BK=32, 512 threads.
// R14/R15 (best measured): As[3](48KB, 2 iters ahead) + Bs[2](16KB, 1 ahead)
// = 64 KB -> 2 blocks/CU; one barrier per K-step after counted vmcnt;
// opaque asm ds_read_b128 + lgkmcnt(0) + sched_barrier; epilogue with j
// innermost (full-line write merging). UNCHANGED this round.
template <int DO_GELU, int DO_REMAP, int OUT_BF16>
__global__ __launch_bounds__(512) void gemm_kernel(const unsigned short* __restrict__ A,
                                                   const unsigned short* __restrict__ Bt,
                                                   const float* __restrict__ bias,
                                                   const float* __restrict__ res,
                                                   void* __restrict__ outv,
                                                   int M, int N, int K, float scale) {
    __shared__ alignas(16) unsigned short As[3][256 * 32];   // 48 KB
    __shared__ alignas(16) unsigned short Bs[2][128 * 32];   // 16 KB

    // bijective XCD swizzle (m204)
    int nwg = gridDim.x * gridDim.y;
    int lid = blockIdx.y * gridDim.x + blockIdx.x;
    int q8 = nwg >> 3, r8 = nwg & 7;
    int xcd = lid & 7, pos = lid >> 3;
    int nlid = (xcd < r8 ? xcd * (q8 + 1) : r8 * (q8 + 1) + (xcd - r8) * q8) + pos;
    int m0 = (nlid / gridDim.x) * 256;
    int n0 = (nlid % gridDim.x) * 128;

    int t = threadIdx.x;
    int lane = t & 63;
    int wv = t >> 6;                  // 0..7
    int wm = (wv >> 1) * 64;          // 4 m-waves: 0,64,128,192
    int wn = (wv & 1) * 64;           // 2 n-waves: 0,64
    int lr = lane & 15;
    int lq = lane >> 4;

    // staging map: tiles are rows x 32 shorts; 16B slot s = (row = s>>2, pc = s&3);
    // phys chunk pc holds global chunk pc ^ xr(row), xr = (r&3)^((r>>2)&3).
    int rowS = t >> 2;                // 0..127
    int pcS = t & 3;
    int xrS = (rowS & 3) ^ ((rowS >> 2) & 3);
    int gcS = ((pcS ^ xrS) << 3);     // shorts offset within the 32-short row

    // reader swizzle: accessed rows ≡ lr (mod 16) -> same xr as lr
    int xrR = (lr & 3) ^ ((lr >> 2) & 3);
    u32 swB = (u32)((lq ^ xrR) << 4); // byte offset within 64-byte row

    floatx4 acc[4][4];
#pragma unroll
    for (int i = 0; i < 4; i++)
#pragma unroll
        for (int j = 0; j < 4; j++) acc[i][j] = (floatx4)0.f;

    const unsigned short* Abase = A + (size_t)(m0 + rowS) * K + gcS;
    const unsigned short* Bbase = Bt + (size_t)(n0 + rowS) * K + gcS;
    size_t arstep = (size_t)128 * K;  // second A slot: rows 128..255

    auto stageA = [&](int buf, int kk) {
        GLOAD_LDS16(Abase + kk, &As[buf][t * 8]);
        GLOAD_LDS16(Abase + arstep + kk, &As[buf][(512 + t) * 8]);
    };
    auto stageB = [&](int buf, int kk) {
        GLOAD_LDS16(Bbase + kk, &Bs[buf][t * 8]);
    };

    // LDS byte bases for opaque reads
    u32 asBase = LDS_U32(&As[0][0]);
    u32 bsBase = LDS_U32(&Bs[0][0]);
    u32 aRow = (u32)((wm + lr) * 64) + swB;   // row stride 64 B
    u32 bRow = (u32)((wn + lr) * 64) + swB;

    const int nk = K >> 5;            // 12 or 48

    // ---- prologue: B0 [1], A0 [2], A1 [2] (5 loads in flight/thread) ----
    stageB(0, 0);
    stageA(0, 0);
    stageA(1, 32);

    for (int kt = 0; kt < nk; ++kt) {
        int ab = kt % 3;
        int bb = kt & 1;
        // retire A(kt)+B(kt); keep A(kt+1)'s 2 loads in flight
        if (kt + 1 < nk) asm volatile("s_waitcnt vmcnt(2)" ::: "memory");
        else             asm volatile("s_waitcnt vmcnt(0)" ::: "memory");
        __builtin_amdgcn_s_barrier();            // tile kt visible to all waves
        // issue next staging FIRST (2-ahead for A, 1-ahead for B), then compute
        if (kt + 1 < nk) stageB(bb ^ 1, (kt + 1) << 5);
        if (kt + 2 < nk) stageA((kt + 2) % 3, (kt + 2) << 5);

        u32 aB = asBase + (u32)ab * 16384u + aRow;
        u32 bB = bsBase + (u32)bb * 8192u + bRow;

        short8 a0[4], b0[4];
        a0[0] = ds_read128<0>(aB);    a0[1] = ds_read128<1024>(aB);
        a0[2] = ds_read128<2048>(aB); a0[3] = ds_read128<3072>(aB);
        b0[0] = ds_read128<0>(bB);    b0[1] = ds_read128<1024>(bB);
        b0[2] = ds_read128<2048>(bB); b0[3] = ds_read128<3072>(bB);

        asm volatile("s_waitcnt lgkmcnt(0)" ::: "memory");   // all 8 reads done
        __builtin_amdgcn_sched_barrier(0);                   // rule #18 fence
        __builtin_amdgcn_s_setprio(1);
#pragma unroll
        for (int i = 0; i < 4; i++)
#pragma unroll
            for (int j = 0; j < 4; j++)
                acc[i][j] = __builtin_amdgcn_mfma_f32_16x16x32_bf16(a0[i], b0[j], acc[i][j], 0, 0, 0);
        __builtin_amdgcn_s_setprio(0);
        // no trailing barrier: staging targets buffers disjoint from those
        // read this iteration; top barrier bounds wave skew; lgkmcnt(0)
        // inside the iteration guarantees reads complete before next barrier.
    }

    // ---- epilogue: j INNERMOST so each row's 4x32B segments merge ----
    float bv[4];
#pragma unroll
    for (int j = 0; j < 4; j++) bv[j] = bias[n0 + wn + j * 16 + lr];
#pragma unroll
    for (int i = 0; i < 4; i++) {
#pragma unroll
        for (int r = 0; r < 4; r++) {
            int grow = m0 + wm + i * 16 + lq * 4 + r;
            int orow = DO_REMAP ? win2nat(grow) : grow;
            size_t rowbase = (size_t)orow * N;
#pragma unroll
            for (int j = 0; j < 4; j++) {
                int gcol = n0 + wn + j * 16 + lr;
                float val = acc[i][j][r] + bv[j];
                if (DO_GELU) val = 0.5f * val * (1.f + erff(val * 0.70710678118654752f));
                val *= scale;
                size_t idx = rowbase + gcol;
                if (res) val += res[idx];
                if (OUT_BF16) ((unsigned short*)outv)[idx] = f2bf(val);
                else          ((float*)outv)[idx] = val;
            }
        }
    }
}

extern "C" void kernel_launch(void* const* d_in, const int* in_sizes, int n_in,
                              void* d_out, int out_size, void* d_ws, size_t ws_size,
                              hipStream_t stream) {
    const float* x          = (const float*)d_in[0];
    const float* kv         = (const float*)d_in[1];
    const int*   rel_index  = (const int*)d_in[2];
    const float* g1         = (const float*)d_in[5];
    const float* b1         = (const float*)d_in[6];
    const float* Wqkv       = (const float*)d_in[7];
    const float* bqkv       = (const float*)d_in[8];
    const float* bias_table = (const float*)d_in[9];
    const float* Wproj      = (const float*)d_in[10];
    const float* bproj      = (const float*)d_in[11];
    const float* g2         = (const float*)d_in[12];
    const float* b2         = (const float*)d_in[13];
    const float* Wfc1       = (const float*)d_in[14];
    const float* bfc1       = (const float*)d_in[15];
    const float* Wfc2       = (const float*)d_in[16];
    const float* bfc2       = (const float*)d_in[17];
    float* out = (float*)d_out;

    char* ws = (char*)d_ws;
    unsigned short* wq_t   = (unsigned short*)(ws);
    unsigned short* wp_t   = (unsigned short*)(ws + 294912);
    unsigned short* wfc1_t = (unsigned short*)(ws + 589824);
    unsigned short* wfc2_t = (unsigned short*)(ws + 1769472);
    float*          biasx  = (float*)(ws + 2949120);
    unsigned short* bufA   = (unsigned short*)(ws + 3080192);
    unsigned short* bufB   = (unsigned short*)(ws + 3080192 + 38535168);

    const int M = 50176;
    const float scale = 0.17677669529663687f;
    const int full_mlp = (ws_size >= (size_t)3080192 + 38535168 + 154140672);

    // merged preprocessing: 4 coalesced tile-transposes + bias expand, ONE dispatch
    prep_kernel<<<1553, 256, 0, stream>>>(Wqkv, Wproj, Wfc1, Wfc2,
                                          rel_index, bias_table,
                                          wq_t, wp_t, wfc1_t, wfc2_t, biasx);

    // LN1 -> windowed (bf16); 8 rows per block
    ln_kernel<<<M / 8, 512, 0, stream>>>(x, g1, b1, bufA, 1);
    // q = (hw @ Wq + bq) * scale -> bufB
    gemm_kernel<0, 0, 1><<<dim3(3, M / 256), 512, 0, stream>>>(bufA, wq_t, bqkv, nullptr, bufB,
                                                               M, 384, 384, scale);
    // attention -> bufA
    attn_kernel<<<16 * NHEAD * 4, 256, 0, stream>>>(bufB, kv, biasx, bufA);
    // proj + window_reverse + residual(x) -> d_out (fp32)
    gemm_kernel<0, 1, 0><<<dim3(3, M / 256), 512, 0, stream>>>(bufA, wp_t, bproj, x, d_out,
                                                               M, 384, 384, 1.f);
    // LN2; 8 rows per block
    ln_kernel<<<M / 8, 512, 0, stream>>>(out, g2, b2, bufA, 0);

    if (full_mlp) {
        gemm_kernel<1, 0, 1><<<dim3(12, M / 256), 512, 0, stream>>>(bufA, wfc1_t, bfc1,
                                                                    nullptr, bufB, M, 1536, 384, 1.f);
        gemm_kernel<0, 0, 0><<<dim3(3, M / 256), 512, 0, stream>>>(bufB, wfc2_t, bfc2,
                                                                   out, out, M, 384, 1536, 1.f);
    } else {
        for (int c = 0; c < 4; c++) {
            size_t ro = (size_t)c * 12544;
            gemm_kernel<1, 0, 1><<<dim3(12, 49), 512, 0, stream>>>(bufA + ro * 384, wfc1_t, bfc1,
                                                                   nullptr, bufB, 12544, 1536, 384, 1.f);
            gemm_kernel<0, 0, 0><<<dim3(3, 49), 512, 0, stream>>>(bufB, wfc2_t, bfc2,
                                                                  out + ro * 384, out + ro * 384,
                                                                  12544, 384, 1536, 1.f);
        }
    }
}